// Round 12
// baseline (135.825 us; speedup 1.0000x reference)
//
#include <hip/hip_runtime.h>
#include <hip/hip_bf16.h>
#include <cstdint>
#include <cstddef>

#define DD 768
#define TSCALE 20.0f

typedef short bf16x8 __attribute__((ext_vector_type(8)));
typedef float f32x4 __attribute__((ext_vector_type(4)));
typedef int   i32x4 __attribute__((ext_vector_type(4)));

__device__ inline float wsum(float v){
  #pragma unroll
  for (int m = 1; m < 64; m <<= 1) v += __shfl_xor(v, m, 64);
  return v;
}
__device__ inline float wmax(float v){
  #pragma unroll
  for (int m = 1; m < 64; m <<= 1) v = fmaxf(v, __shfl_xor(v, m, 64));
  return v;
}

__device__ inline void gload_lds16(const void* g, void* l){
  __builtin_amdgcn_global_load_lds(
      (const __attribute__((address_space(1))) uint32_t*)g,
      (__attribute__((address_space(3))) uint32_t*)l, 16, 0, 0);
}

__device__ inline void store_bf16x4(__hip_bfloat16* p, float4 x){
  __hip_bfloat16 t[4] = {__float2bfloat16(x.x), __float2bfloat16(x.y),
                         __float2bfloat16(x.z), __float2bfloat16(x.w)};
  *(ushort4*)p = *(const ushort4*)t;
}

// quantize 4 normalized floats (|x|<=1) to int8 at scale 127, packed store
__device__ inline void store_i8x4(int8_t* p, float4 x){
  int q0 = __float2int_rn(x.x * 127.f), q1 = __float2int_rn(x.y * 127.f);
  int q2 = __float2int_rn(x.z * 127.f), q3 = __float2int_rn(x.w * 127.f);
  uint32_t w = (uint32_t)(uint8_t)(int8_t)q0 | ((uint32_t)(uint8_t)(int8_t)q1 << 8) |
               ((uint32_t)(uint8_t)(int8_t)q2 << 16) | ((uint32_t)(uint8_t)(int8_t)q3 << 24);
  *(uint32_t*)p = w;
}

// ====== fused normalize + diag argmax/mask + te/ve + i8 emit + lossv, 4 waves ======
__global__ __launch_bounds__(256) void diag_teve(
    const float* __restrict__ obj, const float* __restrict__ txt,
    const float* __restrict__ mdl, const int* __restrict__ lab,
    float* __restrict__ diagmax,
    int8_t* __restrict__ obji8, int8_t* __restrict__ argi8,
    __hip_bfloat16* __restrict__ tenb, __hip_bfloat16* __restrict__ venb,
    float* __restrict__ lossv_arr, float* __restrict__ zr, int C)
{
  __shared__ float so[8][DD];
  __shared__ float sa[3][DD];
  __shared__ float st1[DD];
  __shared__ float smask[3];
  __shared__ int   sbi[3];

  const int i = blockIdx.x, tid = threadIdx.x;
  const int lane = tid & 63, w = tid >> 6;
  const float* ob = obj + (size_t)i * 8 * DD;

  if (tid < 5) zr[i * 5 + tid] = 0.f;   // partition-zero sumexp/rowsum/colsum

  #pragma unroll
  for (int t = 0; t < 2; ++t){
    int k = w * 2 + t;
    float4 v[3]; float ss = 0.f;
    #pragma unroll
    for (int q = 0; q < 3; ++q){
      v[q] = ((const float4*)(ob + k * DD))[lane + q * 64];
      ss += v[q].x * v[q].x + v[q].y * v[q].y + v[q].z * v[q].z + v[q].w * v[q].w;
    }
    ss = wsum(ss);
    float inv = 1.0f / fmaxf(sqrtf(ss), 1e-12f);
    #pragma unroll
    for (int q = 0; q < 3; ++q){
      float4 x = {v[q].x * inv, v[q].y * inv, v[q].z * inv, v[q].w * inv};
      ((float4*)&so[k][0])[lane + q * 64] = x;
      store_i8x4(obji8 + (size_t)(i * 8 + k) * DD + 4 * (lane + q * 64), x);
    }
  }

  float4 a[3];
  {
    int s4 = (w == 0) ? 0 : ((w < 3) ? (w + 1) : 1);
    const float* ap = txt + ((size_t)i * 4 + s4) * DD;
    float ss = 0.f;
    #pragma unroll
    for (int q = 0; q < 3; ++q){
      a[q] = ((const float4*)ap)[lane + q * 64];
      ss += a[q].x * a[q].x + a[q].y * a[q].y + a[q].z * a[q].z + a[q].w * a[q].w;
    }
    ss = wsum(ss);
    float inv = 1.0f / fmaxf(sqrtf(ss), 1e-12f);
    #pragma unroll
    for (int q = 0; q < 3; ++q){
      a[q].x *= inv; a[q].y *= inv; a[q].z *= inv; a[q].w *= inv;
    }
    if (w < 3){
      #pragma unroll
      for (int q = 0; q < 3; ++q){
        ((float4*)&sa[w][0])[lane + q * 64] = a[q];
        store_i8x4(argi8 + (size_t)(i * 3 + w) * DD + 4 * (lane + q * 64), a[q]);
      }
    } else {
      #pragma unroll
      for (int q = 0; q < 3; ++q) ((float4*)st1)[lane + q * 64] = a[q];
    }
  }
  __syncthreads();

  if (w < 3){
    float best = -3.0e38f; int bi = 0;
    for (int k = 0; k < 8; ++k){
      float s = 0.f;
      #pragma unroll
      for (int q = 0; q < 3; ++q){
        float4 v = ((const float4*)&so[k][0])[lane + q * 64];
        s += a[q].x * v.x + a[q].y * v.y + a[q].z * v.z + a[q].w * v.w;
      }
      s = wsum(s);
      if (s > best){ best = s; bi = k; }   // strict > == first-index tie rule
    }
    float dm = best * TSCALE;
    if (lane == 0){
      diagmax[i * 3 + w] = dm;
      smask[w] = (dm > 1.0f) ? 1.0f : 0.0f;
      sbi[w] = bi;
    }
  }
  __syncthreads();

  if (w == 0){
    float m0 = smask[0], m1 = smask[1], m2 = smask[2];
    float4 te[3]; float ss = 0.f;
    #pragma unroll
    for (int q = 0; q < 3; ++q){
      float4 t1v = ((const float4*)st1)[lane + q * 64];
      float4 a0 = ((const float4*)&sa[0][0])[lane + q * 64];
      float4 a1 = ((const float4*)&sa[1][0])[lane + q * 64];
      float4 a2 = ((const float4*)&sa[2][0])[lane + q * 64];
      float4 t;
      t.x = ((t1v.x + m0 * a0.x) + m1 * a1.x) + m2 * a2.x;
      t.y = ((t1v.y + m0 * a0.y) + m1 * a1.y) + m2 * a2.y;
      t.z = ((t1v.z + m0 * a0.z) + m1 * a1.z) + m2 * a2.z;
      t.w = ((t1v.w + m0 * a0.w) + m1 * a1.w) + m2 * a2.w;
      te[q] = t;
      ss += t.x * t.x + t.y * t.y + t.z * t.z + t.w * t.w;
    }
    ss = wsum(ss);
    float inv = 1.0f / fmaxf(sqrtf(ss), 1e-12f);
    #pragma unroll
    for (int q = 0; q < 3; ++q){
      float4 x = {te[q].x * inv, te[q].y * inv, te[q].z * inv, te[q].w * inv};
      store_bf16x4(tenb + (size_t)i * DD + lane * 4 + q * 256, x);
    }
  } else if (w == 1){
    float m0 = smask[0], m1 = smask[1], m2 = smask[2];
    int b0 = sbi[0], b1 = sbi[1], b2 = sbi[2];
    float4 ve[3]; float ss = 0.f;
    #pragma unroll
    for (int q = 0; q < 3; ++q){
      float4 w0 = ((const float4*)&so[b0][0])[lane + q * 64];
      float4 w1 = ((const float4*)&so[b1][0])[lane + q * 64];
      float4 w2 = ((const float4*)&so[b2][0])[lane + q * 64];
      float4 t;
      t.x = ((m0 * w0.x + m1 * w1.x)) + m2 * w2.x;
      t.y = ((m0 * w0.y + m1 * w1.y)) + m2 * w2.y;
      t.z = ((m0 * w0.z + m1 * w1.z)) + m2 * w2.z;
      t.w = ((m0 * w0.w + m1 * w1.w)) + m2 * w2.w;
      ve[q] = t;
      ss += t.x * t.x + t.y * t.y + t.z * t.z + t.w * t.w;
    }
    ss = wsum(ss);
    float inv = 1.0f / fmaxf(sqrtf(ss), 1e-12f);
    #pragma unroll
    for (int q = 0; q < 3; ++q){
      float4 x = {ve[q].x * inv, ve[q].y * inv, ve[q].z * inv, ve[q].w * inv};
      store_bf16x4(venb + (size_t)i * DD + lane * 4 + q * 256, x);
    }
  } else if (w == 3){
    const float* x = mdl + (size_t)i * C;
    float mx = -3.0e38f;
    for (int c = lane; c < C; c += 64) mx = fmaxf(mx, x[c]);
    mx = wmax(mx);
    float s = 0.f;
    for (int c = lane; c < C; c += 64) s += expf(x[c] - mx);
    s = wsum(s);
    if (lane == 0) lossv_arr[i] = logf(s) + mx - x[lab[i]];
  }
}

// ====== unified GEMM kernel: blocks [0,nec) = ec (bf16), rest = wpg (i8) ======
// wpg: BARRIER-FREE K-loop. Block = 64 M-rows x 256 N-cols, 4 waves each owning a
// 64x64 output slice. A panel (64x768B=48KB) staged once, then read-only. Each wave
// ping-pongs its PRIVATE B tile (2x4KB) with per-wave counted vmcnt. No s_barrier
// in the K-loop. A swizzle: ch^=(row&7) over 8 chunks (768B stride, 2-way free).
// B swizzle: ch^=(row>>1)&3 (64B rows, measured 0-conflict).
#define MFMAI8(d, av, bv) d = __builtin_amdgcn_mfma_i32_16x16x64_i8(av, bv, d, 0, 0, 0)

__global__ __launch_bounds__(256, 2) void gemms_fused(
    const int8_t* __restrict__ A, const int8_t* __restrict__ B,
    float* __restrict__ sumexp,
    const __hip_bfloat16* __restrict__ ten, const __hip_bfloat16* __restrict__ ven,
    float* __restrict__ rowsum, float* __restrict__ colsum, float* __restrict__ Ldiag,
    int nec, int necx)
{
  __shared__ char lds[81920];
  const int tid = threadIdx.x;
  const int lane = tid & 63, wid = tid >> 6;

  if ((int)blockIdx.x < nec){
    // ---------------- ec path (identical math to prior rounds) ----------------
    const int bx = blockIdx.x % necx, by = blockIdx.x / necx;
    __hip_bfloat16* As = (__hip_bfloat16*)lds;
    __hip_bfloat16* Bs = (__hip_bfloat16*)(lds + 8192);
    char* AsB = lds; char* BsB = lds + 8192;
    const int wr = wid >> 1, wc = wid & 1;
    f32x4 acc[4][4];
    #pragma unroll
    for (int i2 = 0; i2 < 4; ++i2)
      #pragma unroll
      for (int j = 0; j < 4; ++j) acc[i2][j] = (f32x4){0.f, 0.f, 0.f, 0.f};
    const char* Ab = (const char*)(ten + (size_t)(by * 128) * DD);
    const char* Bb = (const char*)(ven + (size_t)(bx * 128) * DD);
    const int srow = tid >> 2, scol = (tid & 3) * 16;
    const int r = lane & 15, kg = (lane >> 4) * 8;

    for (int kb = 0; kb < DD * 2; kb += 64){
      gload_lds16(Ab + (size_t)srow * (DD*2) + kb + scol, AsB + tid * 16);
      gload_lds16(Ab + (size_t)(srow + 64) * (DD*2) + kb + scol, AsB + 4096 + tid * 16);
      gload_lds16(Bb + (size_t)srow * (DD*2) + kb + scol, BsB + tid * 16);
      gload_lds16(Bb + (size_t)(srow + 64) * (DD*2) + kb + scol, BsB + 4096 + tid * 16);
      __syncthreads();
      bf16x8 af[4], bfr[4];
      #pragma unroll
      for (int mi = 0; mi < 4; ++mi)
        af[mi] = *(const bf16x8*)&As[(wr * 64 + mi * 16 + r) * 32 + kg];
      #pragma unroll
      for (int ni = 0; ni < 4; ++ni)
        bfr[ni] = *(const bf16x8*)&Bs[(wc * 64 + ni * 16 + r) * 32 + kg];
      #pragma unroll
      for (int mi = 0; mi < 4; ++mi)
        #pragma unroll
        for (int ni = 0; ni < 4; ++ni)
          acc[mi][ni] = __builtin_amdgcn_mfma_f32_16x16x32_bf16(af[mi], bfr[ni], acc[mi][ni], 0, 0, 0);
      __syncthreads();
    }
    int rowbase = by * 128 + wr * 64 + ((lane >> 4) << 2);
    float colacc[4] = {0.f, 0.f, 0.f, 0.f};
    #pragma unroll
    for (int mi = 0; mi < 4; ++mi){
      #pragma unroll
      for (int rr = 0; rr < 4; ++rr){
        float s = 0.f;
        #pragma unroll
        for (int ni = 0; ni < 4; ++ni){
          float e = expf(fmaf(acc[mi][ni][rr], TSCALE, -TSCALE));
          s += e; colacc[ni] += e;
        }
        s += __shfl_xor(s, 1, 64); s += __shfl_xor(s, 2, 64);
        s += __shfl_xor(s, 4, 64); s += __shfl_xor(s, 8, 64);
        if ((lane & 15) == 0) atomicAdd(&rowsum[rowbase + mi * 16 + rr], s);
      }
    }
    #pragma unroll
    for (int ni = 0; ni < 4; ++ni){
      float c = colacc[ni];
      c += __shfl_xor(c, 16, 64); c += __shfl_xor(c, 32, 64);
      if (lane < 16) atomicAdd(&colsum[bx * 128 + wc * 64 + ni * 16 + lane], c);
    }
    if (bx == by){
      #pragma unroll
      for (int mi = 0; mi < 4; ++mi)
        #pragma unroll
        for (int ni = 0; ni < 4; ++ni)
          #pragma unroll
          for (int rr = 0; rr < 4; ++rr){
            int grow = wr * 64 + mi * 16 + ((lane >> 4) << 2) + rr;
            int gcol = wc * 64 + ni * 16 + (lane & 15);
            if (grow == gcol) Ldiag[by * 128 + grow] = acc[mi][ni][rr] * TSCALE;
          }
    }
    return;
  }

  // ---------------- wpg path: barrier-free per-wave pipeline ----------------
  const int r = lane & 15, kg = lane >> 4;

  int g = blockIdx.x - nec;                // [0, 2400)
  int bx = (g & 7) * 5 + (g >> 3) % 5;     // 40 N-tiles (256 cols), 5 per XCD
  int by = (g >> 3) / 5;                   // 60 M-tiles (64 rows)

  const int8_t* Abase = A + (size_t)by * 64 * DD;
  const int8_t* Bbase = B + ((size_t)bx * 256 + (size_t)wid * 64) * DD;
  char* Apan = lds;                        // 48 KB shared A panel
  char* Bbuf = lds + 49152 + wid * 8192;   // 2 x 4 KB private per wave

  // Stage A panel (once). chunk c in [0,3072): row=c/48, cc=c%48; swizzle low-3 bits.
  #pragma unroll
  for (int j = 0; j < 12; ++j){
    int c = j * 256 + tid;
    int row = c / 48, cc = c - row * 48;
    int cc2 = (cc & ~7) | ((cc & 7) ^ (row & 7));
    gload_lds16(Abase + (size_t)row * DD + cc2 * 16, Apan + c * 16);
  }

  auto STAGE_B = [&](int p, int kt){
    #pragma unroll
    for (int j = 0; j < 4; ++j){
      int c = j * 64 + lane;               // 256 x 16B chunks = 4 KB
      int row = c >> 2, cc = c & 3;
      int cc2 = cc ^ ((row >> 1) & 3);
      gload_lds16(Bbase + (size_t)row * DD + kt * 64 + cc2 * 16,
                  Bbuf + p * 4096 + c * 16);
    }
  };
  auto LDA = [&](int mi, int t)->i32x4 {
    int row = mi * 16 + r;
    int ch = t * 4 + kg;
    int chs = (ch & ~7) | ((ch & 7) ^ (row & 7));
    return *(const i32x4*)(Apan + row * 768 + chs * 16);
  };
  auto LDB = [&](int p, int ni)->i32x4 {
    int row = ni * 16 + r;
    return *(const i32x4*)(Bbuf + p * 4096 + row * 64 + ((kg ^ ((row >> 1) & 3)) * 16));
  };

  i32x4 acc[4][4];
  #pragma unroll
  for (int mi = 0; mi < 4; ++mi)
    #pragma unroll
    for (int ni = 0; ni < 4; ++ni) acc[mi][ni] = (i32x4){0, 0, 0, 0};

  STAGE_B(0, 0); STAGE_B(1, 1);
  __syncthreads();                         // drains all staging; ONLY barrier

  #pragma unroll
  for (int t = 0; t < 12; ++t){
    if (t >= 2 && t < 11) asm volatile("s_waitcnt vmcnt(4)" ::: "memory");  // stage(t) landed
    else if (t == 11)     asm volatile("s_waitcnt vmcnt(0)" ::: "memory");
    const int p = t & 1;
    i32x4 af[4], bf[4];
    #pragma unroll
    for (int mi = 0; mi < 4; ++mi) af[mi] = LDA(mi, t);
    #pragma unroll
    for (int ni = 0; ni < 4; ++ni) bf[ni] = LDB(p, ni);
    asm volatile("s_waitcnt lgkmcnt(0)" ::: "memory");   // frag reads done before overwrite
    __builtin_amdgcn_sched_barrier(0);
    if (t < 10) STAGE_B(p, t + 2);
    __builtin_amdgcn_s_setprio(1);
    #pragma unroll
    for (int mi = 0; mi < 4; ++mi)
      #pragma unroll
      for (int ni = 0; ni < 4; ++ni) MFMAI8(acc[mi][ni], af[mi], bf[ni]);
    __builtin_amdgcn_s_setprio(0);
  }

  // epilogue: dequant + per-row sum of exp(logit-20)
  const float SC = TSCALE / 16129.0f;   // 20/127^2
  const int rowbase = by * 64 + kg * 4;
  #pragma unroll
  for (int mi = 0; mi < 4; ++mi){
    #pragma unroll
    for (int rr = 0; rr < 4; ++rr){
      float s = 0.f;
      #pragma unroll
      for (int ni = 0; ni < 4; ++ni) s += expf(fmaf((float)acc[mi][ni][rr], SC, -TSCALE));
      s += __shfl_xor(s, 1, 64); s += __shfl_xor(s, 2, 64);
      s += __shfl_xor(s, 4, 64); s += __shfl_xor(s, 8, 64);
      if (r == 0) atomicAdd(&sumexp[rowbase + mi * 16 + rr], s);
    }
  }
}

__global__ __launch_bounds__(256) void finalize_kernel(
    const float* __restrict__ sumexp, const float* __restrict__ diagmax,
    const float* __restrict__ rowsum, const float* __restrict__ colsum,
    const float* __restrict__ Ldiag, const float* __restrict__ lossv_arr,
    float* __restrict__ out, int NB)
{
  int tid = threadIdx.x;
  float p = 0.f;
  for (int r = tid; r < 3 * NB; r += 256) p += logf(sumexp[r]) + TSCALE - diagmax[r];
  p *= (0.3f / (3.0f * NB));
  float q = 0.f, lv = 0.f;
  for (int i2 = tid; i2 < NB; i2 += 256){
    q += (logf(rowsum[i2]) + TSCALE - Ldiag[i2]) + (logf(colsum[i2]) + TSCALE - Ldiag[i2]);
    lv += lossv_arr[i2];
  }
  p += q * (0.25f / NB) + lv * (0.2f / NB);
  __shared__ float red[256];
  red[tid] = p; __syncthreads();
  for (int s = 128; s > 0; s >>= 1){ if (tid < s) red[tid] += red[tid + s]; __syncthreads(); }
  if (tid == 0) out[0] = red[0];
}

extern "C" void kernel_launch(void* const* d_in, const int* in_sizes, int n_in,
                              void* d_out, int out_size, void* d_ws, size_t ws_size,
                              hipStream_t stream) {
  const float* obj = (const float*)d_in[0];
  const float* txt = (const float*)d_in[1];
  const float* mdl = (const float*)d_in[2];
  const int*   lab = (const int*)d_in[3];

  const int NB = in_sizes[1] / (4 * DD);   // 1280
  const int C  = in_sizes[2] / NB;          // 504

  float* ws = (float*)d_ws;
  size_t o = 0;
  int8_t* obji8 = (int8_t*)(ws + o); o += (size_t)NB * 8 * DD / 4;   // bytes/4
  int8_t* argi8 = (int8_t*)(ws + o); o += (size_t)NB * 3 * DD / 4;
  __hip_bfloat16* tenb = (__hip_bfloat16*)(ws + o); o += (size_t)NB * DD / 2;
  __hip_bfloat16* venb = (__hip_bfloat16*)(ws + o); o += (size_t)NB * DD / 2;
  float* diagmax = ws + o; o += (size_t)3 * NB;
  float* Ldiag = ws + o; o += (size_t)NB;
  float* lossv_arr = ws + o; o += (size_t)NB;
  float* zr = ws + o;
  float* sumexp = zr;                      // 3*NB
  float* rowsum = zr + 3 * NB;             // NB
  float* colsum = rowsum + NB;             // NB

  diag_teve<<<NB, 256, 0, stream>>>(obj, txt, mdl, lab, diagmax, obji8, argi8,
                                    tenb, venb, lossv_arr, zr, C);
  const int necx = NB / 128;               // 10
  const int nec = necx * necx;             // 100 ec blocks
  const int nwpg = (NB * 3 / 64) * (NB * 8 / 256);   // 60 x 40 = 2400 wpg blocks
  gemms_fused<<<nec + nwpg, 256, 0, stream>>>(argi8, obji8, sumexp, tenb, venb,
                                              rowsum, colsum, Ldiag, nec, necx);
  finalize_kernel<<<1, 256, 0, stream>>>(sumexp, diagmax, rowsum, colsum, Ldiag, lossv_arr,
                                         (float*)d_out, NB);
}

// Round 13
// 115.872 us; speedup vs baseline: 1.1722x; 1.1722x over previous
//
#include <hip/hip_runtime.h>
#include <hip/hip_bf16.h>
#include <cstdint>
#include <cstddef>

#define DD 768
#define TSCALE 20.0f

typedef short bf16x8 __attribute__((ext_vector_type(8)));
typedef float f32x4 __attribute__((ext_vector_type(4)));
typedef int   i32x4 __attribute__((ext_vector_type(4)));

__device__ inline float wsum(float v){
  #pragma unroll
  for (int m = 1; m < 64; m <<= 1) v += __shfl_xor(v, m, 64);
  return v;
}
__device__ inline float wmax(float v){
  #pragma unroll
  for (int m = 1; m < 64; m <<= 1) v = fmaxf(v, __shfl_xor(v, m, 64));
  return v;
}

__device__ inline void gload_lds16(const void* g, void* l){
  __builtin_amdgcn_global_load_lds(
      (const __attribute__((address_space(1))) uint32_t*)g,
      (__attribute__((address_space(3))) uint32_t*)l, 16, 0, 0);
}

__device__ inline void store_bf16x4(__hip_bfloat16* p, float4 x){
  __hip_bfloat16 t[4] = {__float2bfloat16(x.x), __float2bfloat16(x.y),
                         __float2bfloat16(x.z), __float2bfloat16(x.w)};
  *(ushort4*)p = *(const ushort4*)t;
}

// quantize 4 normalized floats (|x|<=1) to int8 at scale 127, packed store
__device__ inline void store_i8x4(int8_t* p, float4 x){
  int q0 = __float2int_rn(x.x * 127.f), q1 = __float2int_rn(x.y * 127.f);
  int q2 = __float2int_rn(x.z * 127.f), q3 = __float2int_rn(x.w * 127.f);
  uint32_t w = (uint32_t)(uint8_t)(int8_t)q0 | ((uint32_t)(uint8_t)(int8_t)q1 << 8) |
               ((uint32_t)(uint8_t)(int8_t)q2 << 16) | ((uint32_t)(uint8_t)(int8_t)q3 << 24);
  *(uint32_t*)p = w;
}

// ====== norm_obj: normalize all 8*NB obj rows (1 row/wave), emit fp32 + i8 ======
// Also zeroes the atomic accumulator region (5*NB floats) in the low blocks.
__global__ __launch_bounds__(256) void norm_obj(
    const float* __restrict__ obj, float* __restrict__ objn,
    int8_t* __restrict__ obji8, float* __restrict__ zr, int NB)
{
  const int tid = threadIdx.x, lane = tid & 63, w = tid >> 6;
  const int row = blockIdx.x * 4 + w;
  {
    int z = blockIdx.x * 256 + tid;
    if (z < 5 * NB) zr[z] = 0.f;
  }
  const float* src = obj + (size_t)row * DD;
  float4 v[3]; float ss = 0.f;
  #pragma unroll
  for (int q = 0; q < 3; ++q){
    v[q] = ((const float4*)src)[lane + q * 64];
    ss += v[q].x * v[q].x + v[q].y * v[q].y + v[q].z * v[q].z + v[q].w * v[q].w;
  }
  ss = wsum(ss);
  float inv = 1.0f / fmaxf(sqrtf(ss), 1e-12f);
  #pragma unroll
  for (int q = 0; q < 3; ++q){
    float4 x = {v[q].x * inv, v[q].y * inv, v[q].z * inv, v[q].w * inv};
    ((float4*)(objn + (size_t)row * DD))[lane + q * 64] = x;
    store_i8x4(obji8 + (size_t)row * DD + 4 * (lane + q * 64), x);
  }
}

// ====== decision: per video i — args normalize, fp32-exact argmax/mask, te/ve,
// i8 arg emit, lossv. Objects come precomputed (objn) via cooperative LDS load. ======
__global__ __launch_bounds__(256) void decision(
    const float* __restrict__ objn, const float* __restrict__ txt,
    const float* __restrict__ mdl, const int* __restrict__ lab,
    float* __restrict__ diagmax, int8_t* __restrict__ argi8,
    __hip_bfloat16* __restrict__ tenb, __hip_bfloat16* __restrict__ venb,
    float* __restrict__ lossv_arr, int C)
{
  __shared__ float so[8][DD];
  __shared__ float sa[3][DD];
  __shared__ float st1[DD];
  __shared__ float smask[3];
  __shared__ int   sbi[3];

  const int i = blockIdx.x, tid = threadIdx.x;
  const int lane = tid & 63, w = tid >> 6;

  // phase 1: cooperative load of the 8 normalized obj rows (24 KB)
  {
    const float4* src = (const float4*)(objn + (size_t)i * 8 * DD);
    float4* dst = (float4*)so;
    #pragma unroll
    for (int j = 0; j < 6; ++j) dst[j * 256 + tid] = src[j * 256 + tid];
  }

  // phase 2: waves 0-2 normalize arg j=w (keep in regs); wave 3 normalizes t1
  float4 a[3];
  {
    int s4 = (w == 0) ? 0 : ((w < 3) ? (w + 1) : 1);
    const float* ap = txt + ((size_t)i * 4 + s4) * DD;
    float ss = 0.f;
    #pragma unroll
    for (int q = 0; q < 3; ++q){
      a[q] = ((const float4*)ap)[lane + q * 64];
      ss += a[q].x * a[q].x + a[q].y * a[q].y + a[q].z * a[q].z + a[q].w * a[q].w;
    }
    ss = wsum(ss);
    float inv = 1.0f / fmaxf(sqrtf(ss), 1e-12f);
    #pragma unroll
    for (int q = 0; q < 3; ++q){
      a[q].x *= inv; a[q].y *= inv; a[q].z *= inv; a[q].w *= inv;
    }
    if (w < 3){
      #pragma unroll
      for (int q = 0; q < 3; ++q){
        ((float4*)&sa[w][0])[lane + q * 64] = a[q];
        store_i8x4(argi8 + (size_t)(i * 3 + w) * DD + 4 * (lane + q * 64), a[q]);
      }
    } else {
      #pragma unroll
      for (int q = 0; q < 3; ++q) ((float4*)st1)[lane + q * 64] = a[q];
    }
  }
  __syncthreads();

  // phase 3: waves 0-2 compute argmax over own 8 objects (fp32-exact)
  if (w < 3){
    float best = -3.0e38f; int bi = 0;
    for (int k = 0; k < 8; ++k){
      float s = 0.f;
      #pragma unroll
      for (int q = 0; q < 3; ++q){
        float4 v = ((const float4*)&so[k][0])[lane + q * 64];
        s += a[q].x * v.x + a[q].y * v.y + a[q].z * v.z + a[q].w * v.w;
      }
      s = wsum(s);
      if (s > best){ best = s; bi = k; }   // strict > == first-index tie rule
    }
    float dm = best * TSCALE;
    if (lane == 0){
      diagmax[i * 3 + w] = dm;
      smask[w] = (dm > 1.0f) ? 1.0f : 0.0f;
      sbi[w] = bi;
    }
  }
  __syncthreads();

  // phase 4: wave 0 -> te, wave 1 -> ve, wave 3 -> lossv row i
  if (w == 0){
    float m0 = smask[0], m1 = smask[1], m2 = smask[2];
    float4 te[3]; float ss = 0.f;
    #pragma unroll
    for (int q = 0; q < 3; ++q){
      float4 t1v = ((const float4*)st1)[lane + q * 64];
      float4 a0 = ((const float4*)&sa[0][0])[lane + q * 64];
      float4 a1 = ((const float4*)&sa[1][0])[lane + q * 64];
      float4 a2 = ((const float4*)&sa[2][0])[lane + q * 64];
      float4 t;
      t.x = ((t1v.x + m0 * a0.x) + m1 * a1.x) + m2 * a2.x;
      t.y = ((t1v.y + m0 * a0.y) + m1 * a1.y) + m2 * a2.y;
      t.z = ((t1v.z + m0 * a0.z) + m1 * a1.z) + m2 * a2.z;
      t.w = ((t1v.w + m0 * a0.w) + m1 * a1.w) + m2 * a2.w;
      te[q] = t;
      ss += t.x * t.x + t.y * t.y + t.z * t.z + t.w * t.w;
    }
    ss = wsum(ss);
    float inv = 1.0f / fmaxf(sqrtf(ss), 1e-12f);
    #pragma unroll
    for (int q = 0; q < 3; ++q){
      float4 x = {te[q].x * inv, te[q].y * inv, te[q].z * inv, te[q].w * inv};
      store_bf16x4(tenb + (size_t)i * DD + lane * 4 + q * 256, x);
    }
  } else if (w == 1){
    float m0 = smask[0], m1 = smask[1], m2 = smask[2];
    int b0 = sbi[0], b1 = sbi[1], b2 = sbi[2];
    float4 ve[3]; float ss = 0.f;
    #pragma unroll
    for (int q = 0; q < 3; ++q){
      float4 w0 = ((const float4*)&so[b0][0])[lane + q * 64];
      float4 w1 = ((const float4*)&so[b1][0])[lane + q * 64];
      float4 w2 = ((const float4*)&so[b2][0])[lane + q * 64];
      float4 t;
      t.x = ((m0 * w0.x + m1 * w1.x)) + m2 * w2.x;
      t.y = ((m0 * w0.y + m1 * w1.y)) + m2 * w2.y;
      t.z = ((m0 * w0.z + m1 * w1.z)) + m2 * w2.z;
      t.w = ((m0 * w0.w + m1 * w1.w)) + m2 * w2.w;
      ve[q] = t;
      ss += t.x * t.x + t.y * t.y + t.z * t.z + t.w * t.w;
    }
    ss = wsum(ss);
    float inv = 1.0f / fmaxf(sqrtf(ss), 1e-12f);
    #pragma unroll
    for (int q = 0; q < 3; ++q){
      float4 x = {ve[q].x * inv, ve[q].y * inv, ve[q].z * inv, ve[q].w * inv};
      store_bf16x4(venb + (size_t)i * DD + lane * 4 + q * 256, x);
    }
  } else if (w == 3){
    const float* x = mdl + (size_t)i * C;
    float mx = -3.0e38f;
    for (int c = lane; c < C; c += 64) mx = fmaxf(mx, x[c]);
    mx = wmax(mx);
    float s = 0.f;
    for (int c = lane; c < C; c += 64) s += expf(x[c] - mx);
    s = wsum(s);
    if (lane == 0) lossv_arr[i] = logf(s) + mx - x[lab[i]];
  }
}

// ====== unified GEMM kernel: blocks [0,nec) = ec (bf16), rest = wpg (i8) ======
// (r11 configuration, best measured: 128x128 i8 tiles, BK=64B, triple-buffered
// 48KB LDS, counted vmcnt(4), 4 waves, 3 blocks/CU; swizzle c^=(row>>1)&3.)
#define MFMAI8(d, av, bv) d = __builtin_amdgcn_mfma_i32_16x16x64_i8(av, bv, d, 0, 0, 0)

__global__ __launch_bounds__(256, 3) void gemms_fused(
    const int8_t* __restrict__ A, const int8_t* __restrict__ B,
    float* __restrict__ sumexp,
    const __hip_bfloat16* __restrict__ ten, const __hip_bfloat16* __restrict__ ven,
    float* __restrict__ rowsum, float* __restrict__ colsum, float* __restrict__ Ldiag,
    int nec, int necx)
{
  __shared__ char lds[49152];
  const int tid = threadIdx.x;
  const int lane = tid & 63, wid = tid >> 6;

  if ((int)blockIdx.x < nec){
    // ---------------- ec path (identical math to prior rounds) ----------------
    const int bx = blockIdx.x % necx, by = blockIdx.x / necx;
    __hip_bfloat16* As = (__hip_bfloat16*)lds;
    __hip_bfloat16* Bs = (__hip_bfloat16*)(lds + 8192);
    char* AsB = lds; char* BsB = lds + 8192;
    const int wr = wid >> 1, wc = wid & 1;
    f32x4 acc[4][4];
    #pragma unroll
    for (int i2 = 0; i2 < 4; ++i2)
      #pragma unroll
      for (int j = 0; j < 4; ++j) acc[i2][j] = (f32x4){0.f, 0.f, 0.f, 0.f};
    const char* Ab = (const char*)(ten + (size_t)(by * 128) * DD);
    const char* Bb = (const char*)(ven + (size_t)(bx * 128) * DD);
    const int srow = tid >> 2, scol = (tid & 3) * 16;
    const int r = lane & 15, kg = (lane >> 4) * 8;

    for (int kb = 0; kb < DD * 2; kb += 64){
      gload_lds16(Ab + (size_t)srow * (DD*2) + kb + scol, AsB + tid * 16);
      gload_lds16(Ab + (size_t)(srow + 64) * (DD*2) + kb + scol, AsB + 4096 + tid * 16);
      gload_lds16(Bb + (size_t)srow * (DD*2) + kb + scol, BsB + tid * 16);
      gload_lds16(Bb + (size_t)(srow + 64) * (DD*2) + kb + scol, BsB + 4096 + tid * 16);
      __syncthreads();
      bf16x8 af[4], bfr[4];
      #pragma unroll
      for (int mi = 0; mi < 4; ++mi)
        af[mi] = *(const bf16x8*)&As[(wr * 64 + mi * 16 + r) * 32 + kg];
      #pragma unroll
      for (int ni = 0; ni < 4; ++ni)
        bfr[ni] = *(const bf16x8*)&Bs[(wc * 64 + ni * 16 + r) * 32 + kg];
      #pragma unroll
      for (int mi = 0; mi < 4; ++mi)
        #pragma unroll
        for (int ni = 0; ni < 4; ++ni)
          acc[mi][ni] = __builtin_amdgcn_mfma_f32_16x16x32_bf16(af[mi], bfr[ni], acc[mi][ni], 0, 0, 0);
      __syncthreads();
    }
    int rowbase = by * 128 + wr * 64 + ((lane >> 4) << 2);
    float colacc[4] = {0.f, 0.f, 0.f, 0.f};
    #pragma unroll
    for (int mi = 0; mi < 4; ++mi){
      #pragma unroll
      for (int rr = 0; rr < 4; ++rr){
        float s = 0.f;
        #pragma unroll
        for (int ni = 0; ni < 4; ++ni){
          float e = expf(fmaf(acc[mi][ni][rr], TSCALE, -TSCALE));
          s += e; colacc[ni] += e;
        }
        s += __shfl_xor(s, 1, 64); s += __shfl_xor(s, 2, 64);
        s += __shfl_xor(s, 4, 64); s += __shfl_xor(s, 8, 64);
        if ((lane & 15) == 0) atomicAdd(&rowsum[rowbase + mi * 16 + rr], s);
      }
    }
    #pragma unroll
    for (int ni = 0; ni < 4; ++ni){
      float c = colacc[ni];
      c += __shfl_xor(c, 16, 64); c += __shfl_xor(c, 32, 64);
      if (lane < 16) atomicAdd(&colsum[bx * 128 + wc * 64 + ni * 16 + lane], c);
    }
    if (bx == by){
      #pragma unroll
      for (int mi = 0; mi < 4; ++mi)
        #pragma unroll
        for (int ni = 0; ni < 4; ++ni)
          #pragma unroll
          for (int rr = 0; rr < 4; ++rr){
            int grow = wr * 64 + mi * 16 + ((lane >> 4) << 2) + rr;
            int gcol = wc * 64 + ni * 16 + (lane & 15);
            if (grow == gcol) Ldiag[by * 128 + grow] = acc[mi][ni][rr] * TSCALE;
          }
    }
    return;
  }

  // ---------------- wpg path: i8 128x128, 3-buffer counted-vmcnt pipeline ----------------
  const int wr = wid >> 1, wc = wid & 1;      // 2x2 waves, 64x64 each
  const int r = lane & 15, kg = lane >> 4;

  int g = blockIdx.x - nec;                    // [0, 2400)
  int bx = (g & 7) * 10 + (g >> 3) % 10;       // 80 N-tiles, 10 per XCD-chunk
  int by = (g >> 3) / 10;                      // 30 M-tiles

  const int8_t* Abase = A + (size_t)by * 128 * DD;
  const int8_t* Bbase = B + (size_t)bx * 128 * DD;

  const int srow = tid >> 2, sc = tid & 3;     // srow 0..63
  const int ssw = ((sc ^ ((srow >> 1) & 3)) * 16);

  auto STAGE = [&](int p, int kt){
    gload_lds16(Abase + (size_t)srow * DD + kt * 64 + ssw, lds + p * 16384 + tid * 16);
    gload_lds16(Abase + (size_t)(64 + srow) * DD + kt * 64 + ssw, lds + p * 16384 + 4096 + tid * 16);
    gload_lds16(Bbase + (size_t)srow * DD + kt * 64 + ssw, lds + p * 16384 + 8192 + tid * 16);
    gload_lds16(Bbase + (size_t)(64 + srow) * DD + kt * 64 + ssw, lds + p * 16384 + 12288 + tid * 16);
  };
  auto LDA = [&](int p, int mi)->i32x4 {
    int row = wr * 64 + mi * 16 + r;
    return *(const i32x4*)(lds + p * 16384 + row * 64 + ((kg ^ ((row >> 1) & 3)) * 16));
  };
  auto LDB = [&](int p, int ni)->i32x4 {
    int row = wc * 64 + ni * 16 + r;
    return *(const i32x4*)(lds + p * 16384 + 8192 + row * 64 + ((kg ^ ((row >> 1) & 3)) * 16));
  };

  i32x4 acc[4][4];
  #pragma unroll
  for (int mi = 0; mi < 4; ++mi)
    #pragma unroll
    for (int ni = 0; ni < 4; ++ni) acc[mi][ni] = (i32x4){0, 0, 0, 0};

  STAGE(0, 0); STAGE(1, 1);    // 8 loads in flight per thread
  #pragma unroll
  for (int t = 0; t < 12; ++t){
    if (t < 11) asm volatile("s_waitcnt vmcnt(4)" ::: "memory");  // stage(t) landed
    else        asm volatile("s_waitcnt vmcnt(0)" ::: "memory");
    __builtin_amdgcn_s_barrier();
    __builtin_amdgcn_sched_barrier(0);
    if (t < 10) STAGE((t + 2) % 3, t + 2);
    const int p = t % 3;
    i32x4 af[4], bf[4];
    #pragma unroll
    for (int mi = 0; mi < 4; ++mi) af[mi] = LDA(p, mi);
    #pragma unroll
    for (int ni = 0; ni < 4; ++ni) bf[ni] = LDB(p, ni);
    __builtin_amdgcn_s_setprio(1);
    #pragma unroll
    for (int mi = 0; mi < 4; ++mi)
      #pragma unroll
      for (int ni = 0; ni < 4; ++ni) MFMAI8(acc[mi][ni], af[mi], bf[ni]);
    __builtin_amdgcn_s_setprio(0);
  }

  // epilogue: dequant + per-row sum of exp(logit-20)
  const float SC = TSCALE / 16129.0f;   // 20/127^2
  const int rowbase = by * 128 + wr * 64 + kg * 4;
  #pragma unroll
  for (int mi = 0; mi < 4; ++mi){
    #pragma unroll
    for (int rr = 0; rr < 4; ++rr){
      float s = 0.f;
      #pragma unroll
      for (int ni = 0; ni < 4; ++ni) s += expf(fmaf((float)acc[mi][ni][rr], SC, -TSCALE));
      s += __shfl_xor(s, 1, 64); s += __shfl_xor(s, 2, 64);
      s += __shfl_xor(s, 4, 64); s += __shfl_xor(s, 8, 64);
      if (r == 0) atomicAdd(&sumexp[rowbase + mi * 16 + rr], s);
    }
  }
}

__global__ __launch_bounds__(256) void finalize_kernel(
    const float* __restrict__ sumexp, const float* __restrict__ diagmax,
    const float* __restrict__ rowsum, const float* __restrict__ colsum,
    const float* __restrict__ Ldiag, const float* __restrict__ lossv_arr,
    float* __restrict__ out, int NB)
{
  int tid = threadIdx.x;
  float p = 0.f;
  for (int r = tid; r < 3 * NB; r += 256) p += logf(sumexp[r]) + TSCALE - diagmax[r];
  p *= (0.3f / (3.0f * NB));
  float q = 0.f, lv = 0.f;
  for (int i2 = tid; i2 < NB; i2 += 256){
    q += (logf(rowsum[i2]) + TSCALE - Ldiag[i2]) + (logf(colsum[i2]) + TSCALE - Ldiag[i2]);
    lv += lossv_arr[i2];
  }
  p += q * (0.25f / NB) + lv * (0.2f / NB);
  __shared__ float red[256];
  red[tid] = p; __syncthreads();
  for (int s = 128; s > 0; s >>= 1){ if (tid < s) red[tid] += red[tid + s]; __syncthreads(); }
  if (tid == 0) out[0] = red[0];
}

extern "C" void kernel_launch(void* const* d_in, const int* in_sizes, int n_in,
                              void* d_out, int out_size, void* d_ws, size_t ws_size,
                              hipStream_t stream) {
  const float* obj = (const float*)d_in[0];
  const float* txt = (const float*)d_in[1];
  const float* mdl = (const float*)d_in[2];
  const int*   lab = (const int*)d_in[3];

  const int NB = in_sizes[1] / (4 * DD);   // 1280
  const int C  = in_sizes[2] / NB;          // 504

  float* ws = (float*)d_ws;
  size_t o = 0;
  float* objn = ws + o; o += (size_t)NB * 8 * DD;                    // fp32 normalized obj
  int8_t* obji8 = (int8_t*)(ws + o); o += (size_t)NB * 8 * DD / 4;   // bytes/4
  int8_t* argi8 = (int8_t*)(ws + o); o += (size_t)NB * 3 * DD / 4;
  __hip_bfloat16* tenb = (__hip_bfloat16*)(ws + o); o += (size_t)NB * DD / 2;
  __hip_bfloat16* venb = (__hip_bfloat16*)(ws + o); o += (size_t)NB * DD / 2;
  float* diagmax = ws + o; o += (size_t)3 * NB;
  float* Ldiag = ws + o; o += (size_t)NB;
  float* lossv_arr = ws + o; o += (size_t)NB;
  float* zr = ws + o;
  float* sumexp = zr;                      // 3*NB
  float* rowsum = zr + 3 * NB;             // NB
  float* colsum = rowsum + NB;             // NB

  norm_obj<<<NB * 8 / 4, 256, 0, stream>>>(obj, objn, obji8, zr, NB);
  decision<<<NB, 256, 0, stream>>>(objn, txt, mdl, lab, diagmax, argi8,
                                   tenb, venb, lossv_arr, C);
  const int necx = NB / 128;               // 10
  const int nec = necx * necx;             // 100 ec blocks
  const int nwpg = (NB * 3 / 128) * (NB * 8 / 128);   // 2400 wpg blocks
  gemms_fused<<<nec + nwpg, 256, 0, stream>>>(argi8, obji8, sumexp, tenb, venb,
                                              rowsum, colsum, Ldiag, nec, necx);
  finalize_kernel<<<1, 256, 0, stream>>>(sumexp, diagmax, rowsum, colsum, Ldiag, lossv_arr,
                                         (float*)d_out, NB);
}

// Round 14
// 103.627 us; speedup vs baseline: 1.3107x; 1.1182x over previous
//
#include <hip/hip_runtime.h>
#include <hip/hip_bf16.h>
#include <cstdint>
#include <cstddef>

#define DD 768
#define TSCALE 20.0f

typedef short bf16x8 __attribute__((ext_vector_type(8)));
typedef float f32x4 __attribute__((ext_vector_type(4)));
typedef int   i32x4 __attribute__((ext_vector_type(4)));

__device__ inline float wsum(float v){
  #pragma unroll
  for (int m = 1; m < 64; m <<= 1) v += __shfl_xor(v, m, 64);
  return v;
}
__device__ inline float wmax(float v){
  #pragma unroll
  for (int m = 1; m < 64; m <<= 1) v = fmaxf(v, __shfl_xor(v, m, 64));
  return v;
}

__device__ inline void gload_lds16(const void* g, void* l){
  __builtin_amdgcn_global_load_lds(
      (const __attribute__((address_space(1))) uint32_t*)g,
      (__attribute__((address_space(3))) uint32_t*)l, 16, 0, 0);
}

__device__ inline void store_bf16x4(__hip_bfloat16* p, float4 x){
  __hip_bfloat16 t[4] = {__float2bfloat16(x.x), __float2bfloat16(x.y),
                         __float2bfloat16(x.z), __float2bfloat16(x.w)};
  *(ushort4*)p = *(const ushort4*)t;
}

// quantize 4 normalized floats (|x|<=1) to int8 at scale 127, packed store
__device__ inline void store_i8x4(int8_t* p, float4 x){
  int q0 = __float2int_rn(x.x * 127.f), q1 = __float2int_rn(x.y * 127.f);
  int q2 = __float2int_rn(x.z * 127.f), q3 = __float2int_rn(x.w * 127.f);
  uint32_t w = (uint32_t)(uint8_t)(int8_t)q0 | ((uint32_t)(uint8_t)(int8_t)q1 << 8) |
               ((uint32_t)(uint8_t)(int8_t)q2 << 16) | ((uint32_t)(uint8_t)(int8_t)q3 << 24);
  *(uint32_t*)p = w;
}

// ====== fused normalize + diag argmax/mask + te/ve + i8 emit + lossv, 8 waves ======
// Wave w (0-7): normalizes obj row w. Waves 0-2: arg j=w (normalize, i8, argmax).
// Wave 3: t1 normalize, then lossv combine. Waves 4-7: lossv partial max/sum.
// Wave 0: te assembly; wave 1: ve assembly. Zeroes zr (5 floats/block).
__global__ __launch_bounds__(512) void diag_teve(
    const float* __restrict__ obj, const float* __restrict__ txt,
    const float* __restrict__ mdl, const int* __restrict__ lab,
    float* __restrict__ diagmax,
    int8_t* __restrict__ obji8, int8_t* __restrict__ argi8,
    __hip_bfloat16* __restrict__ tenb, __hip_bfloat16* __restrict__ venb,
    float* __restrict__ lossv_arr, float* __restrict__ zr, int C)
{
  __shared__ float so[8][DD];
  __shared__ float sa[3][DD];
  __shared__ float st1[DD];
  __shared__ float smask[3];
  __shared__ int   sbi[3];
  __shared__ float pmax[4], psum[4];

  const int i = blockIdx.x, tid = threadIdx.x;
  const int lane = tid & 63, w = tid >> 6;

  if (tid < 5) zr[i * 5 + tid] = 0.f;   // zero sumexp/rowsum/colsum partitions

  // phase 1: wave w normalizes obj row w (fp32-exact, same wsum order as before)
  {
    const float* src = obj + ((size_t)i * 8 + w) * DD;
    float4 v[3]; float ss = 0.f;
    #pragma unroll
    for (int q = 0; q < 3; ++q){
      v[q] = ((const float4*)src)[lane + q * 64];
      ss += v[q].x * v[q].x + v[q].y * v[q].y + v[q].z * v[q].z + v[q].w * v[q].w;
    }
    ss = wsum(ss);
    float inv = 1.0f / fmaxf(sqrtf(ss), 1e-12f);
    #pragma unroll
    for (int q = 0; q < 3; ++q){
      float4 x = {v[q].x * inv, v[q].y * inv, v[q].z * inv, v[q].w * inv};
      ((float4*)&so[w][0])[lane + q * 64] = x;
      store_i8x4(obji8 + ((size_t)i * 8 + w) * DD + 4 * (lane + q * 64), x);
    }
  }

  // phase 2: waves 0-2 normalize arg j=w; wave 3 normalizes t1; waves 4-7 lossv partials
  float4 a[3];
  if (w < 4){
    int s4 = (w == 0) ? 0 : ((w < 3) ? (w + 1) : 1);
    const float* ap = txt + ((size_t)i * 4 + s4) * DD;
    float ss = 0.f;
    #pragma unroll
    for (int q = 0; q < 3; ++q){
      a[q] = ((const float4*)ap)[lane + q * 64];
      ss += a[q].x * a[q].x + a[q].y * a[q].y + a[q].z * a[q].z + a[q].w * a[q].w;
    }
    ss = wsum(ss);
    float inv = 1.0f / fmaxf(sqrtf(ss), 1e-12f);
    #pragma unroll
    for (int q = 0; q < 3; ++q){
      a[q].x *= inv; a[q].y *= inv; a[q].z *= inv; a[q].w *= inv;
    }
    if (w < 3){
      #pragma unroll
      for (int q = 0; q < 3; ++q){
        ((float4*)&sa[w][0])[lane + q * 64] = a[q];
        store_i8x4(argi8 + (size_t)(i * 3 + w) * DD + 4 * (lane + q * 64), a[q]);
      }
    } else {
      #pragma unroll
      for (int q = 0; q < 3; ++q) ((float4*)st1)[lane + q * 64] = a[q];
    }
  } else {
    // lossv partial: wave W covers c = lane + W*64, stride 256
    const int W = w - 4;
    const float* x = mdl + (size_t)i * C;
    float mx = -3.0e38f;
    for (int c = lane + W * 64; c < C; c += 256) mx = fmaxf(mx, x[c]);
    mx = wmax(mx);
    float s = 0.f;
    for (int c = lane + W * 64; c < C; c += 256) s += expf(x[c] - mx);
    s = wsum(s);
    if (lane == 0){ pmax[W] = mx; psum[W] = s; }
  }
  __syncthreads();

  // phase 3: waves 0-2 argmax over own 8 objects (fp32-exact); wave 3 combines lossv
  if (w < 3){
    float best = -3.0e38f; int bi = 0;
    for (int k = 0; k < 8; ++k){
      float s = 0.f;
      #pragma unroll
      for (int q = 0; q < 3; ++q){
        float4 v = ((const float4*)&so[k][0])[lane + q * 64];
        s += a[q].x * v.x + a[q].y * v.y + a[q].z * v.z + a[q].w * v.w;
      }
      s = wsum(s);
      if (s > best){ best = s; bi = k; }   // strict > == first-index tie rule
    }
    float dm = best * TSCALE;
    if (lane == 0){
      diagmax[i * 3 + w] = dm;
      smask[w] = (dm > 1.0f) ? 1.0f : 0.0f;
      sbi[w] = bi;
    }
  } else if (w == 3 && lane == 0){
    float M = fmaxf(fmaxf(pmax[0], pmax[1]), fmaxf(pmax[2], pmax[3]));
    float S = psum[0] * expf(pmax[0] - M) + psum[1] * expf(pmax[1] - M)
            + psum[2] * expf(pmax[2] - M) + psum[3] * expf(pmax[3] - M);
    lossv_arr[i] = logf(S) + M - mdl[(size_t)i * C + lab[i]];
  }
  __syncthreads();

  // phase 4: wave 0 -> te, wave 1 -> ve
  if (w == 0){
    float m0 = smask[0], m1 = smask[1], m2 = smask[2];
    float4 te[3]; float ss = 0.f;
    #pragma unroll
    for (int q = 0; q < 3; ++q){
      float4 t1v = ((const float4*)st1)[lane + q * 64];
      float4 a0 = ((const float4*)&sa[0][0])[lane + q * 64];
      float4 a1 = ((const float4*)&sa[1][0])[lane + q * 64];
      float4 a2 = ((const float4*)&sa[2][0])[lane + q * 64];
      float4 t;
      t.x = ((t1v.x + m0 * a0.x) + m1 * a1.x) + m2 * a2.x;
      t.y = ((t1v.y + m0 * a0.y) + m1 * a1.y) + m2 * a2.y;
      t.z = ((t1v.z + m0 * a0.z) + m1 * a1.z) + m2 * a2.z;
      t.w = ((t1v.w + m0 * a0.w) + m1 * a1.w) + m2 * a2.w;
      te[q] = t;
      ss += t.x * t.x + t.y * t.y + t.z * t.z + t.w * t.w;
    }
    ss = wsum(ss);
    float inv = 1.0f / fmaxf(sqrtf(ss), 1e-12f);
    #pragma unroll
    for (int q = 0; q < 3; ++q){
      float4 x = {te[q].x * inv, te[q].y * inv, te[q].z * inv, te[q].w * inv};
      store_bf16x4(tenb + (size_t)i * DD + lane * 4 + q * 256, x);
    }
  } else if (w == 1){
    float m0 = smask[0], m1 = smask[1], m2 = smask[2];
    int b0 = sbi[0], b1 = sbi[1], b2 = sbi[2];
    float4 ve[3]; float ss = 0.f;
    #pragma unroll
    for (int q = 0; q < 3; ++q){
      float4 w0 = ((const float4*)&so[b0][0])[lane + q * 64];
      float4 w1 = ((const float4*)&so[b1][0])[lane + q * 64];
      float4 w2 = ((const float4*)&so[b2][0])[lane + q * 64];
      float4 t;
      t.x = ((m0 * w0.x + m1 * w1.x)) + m2 * w2.x;
      t.y = ((m0 * w0.y + m1 * w1.y)) + m2 * w2.y;
      t.z = ((m0 * w0.z + m1 * w1.z)) + m2 * w2.z;
      t.w = ((m0 * w0.w + m1 * w1.w)) + m2 * w2.w;
      ve[q] = t;
      ss += t.x * t.x + t.y * t.y + t.z * t.z + t.w * t.w;
    }
    ss = wsum(ss);
    float inv = 1.0f / fmaxf(sqrtf(ss), 1e-12f);
    #pragma unroll
    for (int q = 0; q < 3; ++q){
      float4 x = {ve[q].x * inv, ve[q].y * inv, ve[q].z * inv, ve[q].w * inv};
      store_bf16x4(venb + (size_t)i * DD + lane * 4 + q * 256, x);
    }
  }
}

// ====== unified GEMM kernel: blocks [0,nec) = ec (bf16), rest = wpg (i8) ======
// (r11 best-measured config: 128x128 i8 tiles, BK=64B, triple-buffered 48KB LDS,
// counted vmcnt(4), 4 waves, 3 blocks/CU; swizzle c^=(row>>1)&3.)
#define MFMAI8(d, av, bv) d = __builtin_amdgcn_mfma_i32_16x16x64_i8(av, bv, d, 0, 0, 0)

__global__ __launch_bounds__(256, 3) void gemms_fused(
    const int8_t* __restrict__ A, const int8_t* __restrict__ B,
    float* __restrict__ sumexp,
    const __hip_bfloat16* __restrict__ ten, const __hip_bfloat16* __restrict__ ven,
    float* __restrict__ rowsum, float* __restrict__ colsum, float* __restrict__ Ldiag,
    int nec, int necx)
{
  __shared__ char lds[49152];
  const int tid = threadIdx.x;
  const int lane = tid & 63, wid = tid >> 6;

  if ((int)blockIdx.x < nec){
    // ---------------- ec path ----------------
    const int bx = blockIdx.x % necx, by = blockIdx.x / necx;
    __hip_bfloat16* As = (__hip_bfloat16*)lds;
    __hip_bfloat16* Bs = (__hip_bfloat16*)(lds + 8192);
    char* AsB = lds; char* BsB = lds + 8192;
    const int wr = wid >> 1, wc = wid & 1;
    f32x4 acc[4][4];
    #pragma unroll
    for (int i2 = 0; i2 < 4; ++i2)
      #pragma unroll
      for (int j = 0; j < 4; ++j) acc[i2][j] = (f32x4){0.f, 0.f, 0.f, 0.f};
    const char* Ab = (const char*)(ten + (size_t)(by * 128) * DD);
    const char* Bb = (const char*)(ven + (size_t)(bx * 128) * DD);
    const int srow = tid >> 2, scol = (tid & 3) * 16;
    const int r = lane & 15, kg = (lane >> 4) * 8;

    for (int kb = 0; kb < DD * 2; kb += 64){
      gload_lds16(Ab + (size_t)srow * (DD*2) + kb + scol, AsB + tid * 16);
      gload_lds16(Ab + (size_t)(srow + 64) * (DD*2) + kb + scol, AsB + 4096 + tid * 16);
      gload_lds16(Bb + (size_t)srow * (DD*2) + kb + scol, BsB + tid * 16);
      gload_lds16(Bb + (size_t)(srow + 64) * (DD*2) + kb + scol, BsB + 4096 + tid * 16);
      __syncthreads();
      bf16x8 af[4], bfr[4];
      #pragma unroll
      for (int mi = 0; mi < 4; ++mi)
        af[mi] = *(const bf16x8*)&As[(wr * 64 + mi * 16 + r) * 32 + kg];
      #pragma unroll
      for (int ni = 0; ni < 4; ++ni)
        bfr[ni] = *(const bf16x8*)&Bs[(wc * 64 + ni * 16 + r) * 32 + kg];
      #pragma unroll
      for (int mi = 0; mi < 4; ++mi)
        #pragma unroll
        for (int ni = 0; ni < 4; ++ni)
          acc[mi][ni] = __builtin_amdgcn_mfma_f32_16x16x32_bf16(af[mi], bfr[ni], acc[mi][ni], 0, 0, 0);
      __syncthreads();
    }
    int rowbase = by * 128 + wr * 64 + ((lane >> 4) << 2);
    float colacc[4] = {0.f, 0.f, 0.f, 0.f};
    #pragma unroll
    for (int mi = 0; mi < 4; ++mi){
      #pragma unroll
      for (int rr = 0; rr < 4; ++rr){
        float s = 0.f;
        #pragma unroll
        for (int ni = 0; ni < 4; ++ni){
          float e = expf(fmaf(acc[mi][ni][rr], TSCALE, -TSCALE));
          s += e; colacc[ni] += e;
        }
        s += __shfl_xor(s, 1, 64); s += __shfl_xor(s, 2, 64);
        s += __shfl_xor(s, 4, 64); s += __shfl_xor(s, 8, 64);
        if ((lane & 15) == 0) atomicAdd(&rowsum[rowbase + mi * 16 + rr], s);
      }
    }
    #pragma unroll
    for (int ni = 0; ni < 4; ++ni){
      float c = colacc[ni];
      c += __shfl_xor(c, 16, 64); c += __shfl_xor(c, 32, 64);
      if (lane < 16) atomicAdd(&colsum[bx * 128 + wc * 64 + ni * 16 + lane], c);
    }
    if (bx == by){
      #pragma unroll
      for (int mi = 0; mi < 4; ++mi)
        #pragma unroll
        for (int ni = 0; ni < 4; ++ni)
          #pragma unroll
          for (int rr = 0; rr < 4; ++rr){
            int grow = wr * 64 + mi * 16 + ((lane >> 4) << 2) + rr;
            int gcol = wc * 64 + ni * 16 + (lane & 15);
            if (grow == gcol) Ldiag[by * 128 + grow] = acc[mi][ni][rr] * TSCALE;
          }
    }
    return;
  }

  // ---------------- wpg path: i8 128x128, 3-buffer counted-vmcnt pipeline ----------------
  const int wr = wid >> 1, wc = wid & 1;      // 2x2 waves, 64x64 each
  const int r = lane & 15, kg = lane >> 4;

  int g = blockIdx.x - nec;                    // [0, 2400)
  int bx = (g & 7) * 10 + (g >> 3) % 10;       // 80 N-tiles, 10 per XCD-chunk
  int by = (g >> 3) / 10;                      // 30 M-tiles

  const int8_t* Abase = A + (size_t)by * 128 * DD;
  const int8_t* Bbase = B + (size_t)bx * 128 * DD;

  const int srow = tid >> 2, sc = tid & 3;     // srow 0..63
  const int ssw = ((sc ^ ((srow >> 1) & 3)) * 16);

  auto STAGE = [&](int p, int kt){
    gload_lds16(Abase + (size_t)srow * DD + kt * 64 + ssw, lds + p * 16384 + tid * 16);
    gload_lds16(Abase + (size_t)(64 + srow) * DD + kt * 64 + ssw, lds + p * 16384 + 4096 + tid * 16);
    gload_lds16(Bbase + (size_t)srow * DD + kt * 64 + ssw, lds + p * 16384 + 8192 + tid * 16);
    gload_lds16(Bbase + (size_t)(64 + srow) * DD + kt * 64 + ssw, lds + p * 16384 + 12288 + tid * 16);
  };
  auto LDA = [&](int p, int mi)->i32x4 {
    int row = wr * 64 + mi * 16 + r;
    return *(const i32x4*)(lds + p * 16384 + row * 64 + ((kg ^ ((row >> 1) & 3)) * 16));
  };
  auto LDB = [&](int p, int ni)->i32x4 {
    int row = wc * 64 + ni * 16 + r;
    return *(const i32x4*)(lds + p * 16384 + 8192 + row * 64 + ((kg ^ ((row >> 1) & 3)) * 16));
  };

  i32x4 acc[4][4];
  #pragma unroll
  for (int mi = 0; mi < 4; ++mi)
    #pragma unroll
    for (int ni = 0; ni < 4; ++ni) acc[mi][ni] = (i32x4){0, 0, 0, 0};

  STAGE(0, 0); STAGE(1, 1);    // 8 loads in flight per thread
  #pragma unroll
  for (int t = 0; t < 12; ++t){
    if (t < 11) asm volatile("s_waitcnt vmcnt(4)" ::: "memory");  // stage(t) landed
    else        asm volatile("s_waitcnt vmcnt(0)" ::: "memory");
    __builtin_amdgcn_s_barrier();
    __builtin_amdgcn_sched_barrier(0);
    if (t < 10) STAGE((t + 2) % 3, t + 2);
    const int p = t % 3;
    i32x4 af[4], bf[4];
    #pragma unroll
    for (int mi = 0; mi < 4; ++mi) af[mi] = LDA(p, mi);
    #pragma unroll
    for (int ni = 0; ni < 4; ++ni) bf[ni] = LDB(p, ni);
    __builtin_amdgcn_s_setprio(1);
    #pragma unroll
    for (int mi = 0; mi < 4; ++mi)
      #pragma unroll
      for (int ni = 0; ni < 4; ++ni) MFMAI8(acc[mi][ni], af[mi], bf[ni]);
    __builtin_amdgcn_s_setprio(0);
  }

  // epilogue: dequant + per-row sum of exp(logit-20)
  const float SC = TSCALE / 16129.0f;   // 20/127^2
  const int rowbase = by * 128 + wr * 64 + kg * 4;
  #pragma unroll
  for (int mi = 0; mi < 4; ++mi){
    #pragma unroll
    for (int rr = 0; rr < 4; ++rr){
      float s = 0.f;
      #pragma unroll
      for (int ni = 0; ni < 4; ++ni) s += expf(fmaf((float)acc[mi][ni][rr], SC, -TSCALE));
      s += __shfl_xor(s, 1, 64); s += __shfl_xor(s, 2, 64);
      s += __shfl_xor(s, 4, 64); s += __shfl_xor(s, 8, 64);
      if (r == 0) atomicAdd(&sumexp[rowbase + mi * 16 + rr], s);
    }
  }
}

__global__ __launch_bounds__(256) void finalize_kernel(
    const float* __restrict__ sumexp, const float* __restrict__ diagmax,
    const float* __restrict__ rowsum, const float* __restrict__ colsum,
    const float* __restrict__ Ldiag, const float* __restrict__ lossv_arr,
    float* __restrict__ out, int NB)
{
  int tid = threadIdx.x;
  float p = 0.f;
  for (int r = tid; r < 3 * NB; r += 256) p += logf(sumexp[r]) + TSCALE - diagmax[r];
  p *= (0.3f / (3.0f * NB));
  float q = 0.f, lv = 0.f;
  for (int i2 = tid; i2 < NB; i2 += 256){
    q += (logf(rowsum[i2]) + TSCALE - Ldiag[i2]) + (logf(colsum[i2]) + TSCALE - Ldiag[i2]);
    lv += lossv_arr[i2];
  }
  p += q * (0.25f / NB) + lv * (0.2f / NB);
  __shared__ float red[256];
  red[tid] = p; __syncthreads();
  for (int s = 128; s > 0; s >>= 1){ if (tid < s) red[tid] += red[tid + s]; __syncthreads(); }
  if (tid == 0) out[0] = red[0];
}

extern "C" void kernel_launch(void* const* d_in, const int* in_sizes, int n_in,
                              void* d_out, int out_size, void* d_ws, size_t ws_size,
                              hipStream_t stream) {
  const float* obj = (const float*)d_in[0];
  const float* txt = (const float*)d_in[1];
  const float* mdl = (const float*)d_in[2];
  const int*   lab = (const int*)d_in[3];

  const int NB = in_sizes[1] / (4 * DD);   // 1280
  const int C  = in_sizes[2] / NB;          // 504

  float* ws = (float*)d_ws;
  size_t o = 0;
  int8_t* obji8 = (int8_t*)(ws + o); o += (size_t)NB * 8 * DD / 4;   // bytes/4
  int8_t* argi8 = (int8_t*)(ws + o); o += (size_t)NB * 3 * DD / 4;
  __hip_bfloat16* tenb = (__hip_bfloat16*)(ws + o); o += (size_t)NB * DD / 2;
  __hip_bfloat16* venb = (__hip_bfloat16*)(ws + o); o += (size_t)NB * DD / 2;
  float* diagmax = ws + o; o += (size_t)3 * NB;
  float* Ldiag = ws + o; o += (size_t)NB;
  float* lossv_arr = ws + o; o += (size_t)NB;
  float* zr = ws + o;
  float* sumexp = zr;                      // 3*NB
  float* rowsum = zr + 3 * NB;             // NB
  float* colsum = rowsum + NB;             // NB

  diag_teve<<<NB, 512, 0, stream>>>(obj, txt, mdl, lab, diagmax, obji8, argi8,
                                    tenb, venb, lossv_arr, zr, C);
  const int necx = NB / 128;               // 10
  const int nec = necx * necx;             // 100 ec blocks
  const int nwpg = (NB * 3 / 128) * (NB * 8 / 128);   // 2400 wpg blocks
  gemms_fused<<<nec + nwpg, 256, 0, stream>>>(argi8, obji8, sumexp, tenb, venb,
                                              rowsum, colsum, Ldiag, nec, necx);
  finalize_kernel<<<1, 256, 0, stream>>>(sumexp, diagmax, rowsum, colsum, Ldiag, lossv_arr,
                                         (float*)d_out, NB);
}

// Round 15
// 102.143 us; speedup vs baseline: 1.3298x; 1.0145x over previous
//
#include <hip/hip_runtime.h>
#include <hip/hip_bf16.h>
#include <cstdint>
#include <cstddef>

#define DD 768
#define TSCALE 20.0f

typedef short bf16x8 __attribute__((ext_vector_type(8)));
typedef float f32x4 __attribute__((ext_vector_type(4)));
typedef int   i32x4 __attribute__((ext_vector_type(4)));

__device__ inline float wsum(float v){
  #pragma unroll
  for (int m = 1; m < 64; m <<= 1) v += __shfl_xor(v, m, 64);
  return v;
}
__device__ inline float wmax(float v){
  #pragma unroll
  for (int m = 1; m < 64; m <<= 1) v = fmaxf(v, __shfl_xor(v, m, 64));
  return v;
}

__device__ inline void gload_lds16(const void* g, void* l){
  __builtin_amdgcn_global_load_lds(
      (const __attribute__((address_space(1))) uint32_t*)g,
      (__attribute__((address_space(3))) uint32_t*)l, 16, 0, 0);
}

__device__ inline void store_bf16x4(__hip_bfloat16* p, float4 x){
  __hip_bfloat16 t[4] = {__float2bfloat16(x.x), __float2bfloat16(x.y),
                         __float2bfloat16(x.z), __float2bfloat16(x.w)};
  *(ushort4*)p = *(const ushort4*)t;
}

// quantize 4 normalized floats (|x|<=1) to int8 at scale 127, packed store
__device__ inline void store_i8x4(int8_t* p, float4 x){
  int q0 = __float2int_rn(x.x * 127.f), q1 = __float2int_rn(x.y * 127.f);
  int q2 = __float2int_rn(x.z * 127.f), q3 = __float2int_rn(x.w * 127.f);
  uint32_t w = (uint32_t)(uint8_t)(int8_t)q0 | ((uint32_t)(uint8_t)(int8_t)q1 << 8) |
               ((uint32_t)(uint8_t)(int8_t)q2 << 16) | ((uint32_t)(uint8_t)(int8_t)q3 << 24);
  *(uint32_t*)p = w;
}

// ====== fused normalize + diag argmax/mask + te/ve + i8 emit + lossv, 8 waves ======
// Phase 1: wave w normalizes obj row w. Phase 2: waves 0-2 arg j=w; wave 3 t1;
// waves 4-7 lossv partials. Phase 3 (PARALLEL): wave w computes dot(sa[j], so[w])
// for j=0..2 -> sdot; wave 3 also combines lossv. Phase 4a: wave-0 lanes 0-2 do
// the 8-way argmax per j (same compare order). Phase 4b: wave 0 te, wave 1 ve.
// launch_bounds(512,2) caps VGPR at 128 -> 2 blocks/CU (was 1).
__global__ __launch_bounds__(512, 2) void diag_teve(
    const float* __restrict__ obj, const float* __restrict__ txt,
    const float* __restrict__ mdl, const int* __restrict__ lab,
    float* __restrict__ diagmax,
    int8_t* __restrict__ obji8, int8_t* __restrict__ argi8,
    __hip_bfloat16* __restrict__ tenb, __hip_bfloat16* __restrict__ venb,
    float* __restrict__ lossv_arr, float* __restrict__ zr, int C)
{
  __shared__ float so[8][DD];
  __shared__ float sa[3][DD];
  __shared__ float st1[DD];
  __shared__ float sdot[3][8];
  __shared__ float smask[3];
  __shared__ int   sbi[3];
  __shared__ float pmax[4], psum[4];

  const int i = blockIdx.x, tid = threadIdx.x;
  const int lane = tid & 63, w = tid >> 6;

  if (tid < 5) zr[i * 5 + tid] = 0.f;   // zero sumexp/rowsum/colsum partitions

  // phase 1: wave w normalizes obj row w (fp32-exact, same wsum order)
  {
    const float* src = obj + ((size_t)i * 8 + w) * DD;
    float4 v[3]; float ss = 0.f;
    #pragma unroll
    for (int q = 0; q < 3; ++q){
      v[q] = ((const float4*)src)[lane + q * 64];
      ss += v[q].x * v[q].x + v[q].y * v[q].y + v[q].z * v[q].z + v[q].w * v[q].w;
    }
    ss = wsum(ss);
    float inv = 1.0f / fmaxf(sqrtf(ss), 1e-12f);
    #pragma unroll
    for (int q = 0; q < 3; ++q){
      float4 x = {v[q].x * inv, v[q].y * inv, v[q].z * inv, v[q].w * inv};
      ((float4*)&so[w][0])[lane + q * 64] = x;
      store_i8x4(obji8 + ((size_t)i * 8 + w) * DD + 4 * (lane + q * 64), x);
    }
  }

  // phase 2: waves 0-2 normalize arg j=w; wave 3 t1; waves 4-7 lossv partials
  if (w < 4){
    int s4 = (w == 0) ? 0 : ((w < 3) ? (w + 1) : 1);
    const float* ap = txt + ((size_t)i * 4 + s4) * DD;
    float4 a[3]; float ss = 0.f;
    #pragma unroll
    for (int q = 0; q < 3; ++q){
      a[q] = ((const float4*)ap)[lane + q * 64];
      ss += a[q].x * a[q].x + a[q].y * a[q].y + a[q].z * a[q].z + a[q].w * a[q].w;
    }
    ss = wsum(ss);
    float inv = 1.0f / fmaxf(sqrtf(ss), 1e-12f);
    #pragma unroll
    for (int q = 0; q < 3; ++q){
      a[q].x *= inv; a[q].y *= inv; a[q].z *= inv; a[q].w *= inv;
    }
    if (w < 3){
      #pragma unroll
      for (int q = 0; q < 3; ++q){
        ((float4*)&sa[w][0])[lane + q * 64] = a[q];
        store_i8x4(argi8 + (size_t)(i * 3 + w) * DD + 4 * (lane + q * 64), a[q]);
      }
    } else {
      #pragma unroll
      for (int q = 0; q < 3; ++q) ((float4*)st1)[lane + q * 64] = a[q];
    }
  } else {
    const int W = w - 4;
    const float* x = mdl + (size_t)i * C;
    float mx = -3.0e38f;
    for (int c = lane + W * 64; c < C; c += 256) mx = fmaxf(mx, x[c]);
    mx = wmax(mx);
    float s = 0.f;
    for (int c = lane + W * 64; c < C; c += 256) s += expf(x[c] - mx);
    s = wsum(s);
    if (lane == 0){ pmax[W] = mx; psum[W] = s; }
  }
  __syncthreads();

  // phase 3 (parallel): wave w computes dot(sa[j], so[w]) for j=0..2.
  // Per-lane partial is the same q-ordered fma chain as before -> identical fp32.
  {
    float4 v[3];
    #pragma unroll
    for (int q = 0; q < 3; ++q) v[q] = ((const float4*)&so[w][0])[lane + q * 64];
    #pragma unroll
    for (int j = 0; j < 3; ++j){
      float s = 0.f;
      #pragma unroll
      for (int q = 0; q < 3; ++q){
        float4 aq = ((const float4*)&sa[j][0])[lane + q * 64];
        s += aq.x * v[q].x + aq.y * v[q].y + aq.z * v[q].z + aq.w * v[q].w;
      }
      s = wsum(s);
      if (lane == 0) sdot[j][w] = s;
    }
    if (w == 3 && lane == 0){
      float M = fmaxf(fmaxf(pmax[0], pmax[1]), fmaxf(pmax[2], pmax[3]));
      float S = psum[0] * expf(pmax[0] - M) + psum[1] * expf(pmax[1] - M)
              + psum[2] * expf(pmax[2] - M) + psum[3] * expf(pmax[3] - M);
      lossv_arr[i] = logf(S) + M - mdl[(size_t)i * C + lab[i]];
    }
  }
  __syncthreads();

  // phase 4a: wave-0 lanes 0-2: argmax over k=0..7, strict > (first-index ties)
  if (w == 0 && lane < 3){
    float best = -3.0e38f; int bi = 0;
    #pragma unroll
    for (int k = 0; k < 8; ++k){
      float s = sdot[lane][k];
      if (s > best){ best = s; bi = k; }
    }
    float dm = best * TSCALE;
    diagmax[i * 3 + lane] = dm;
    smask[lane] = (dm > 1.0f) ? 1.0f : 0.0f;
    sbi[lane] = bi;
  }
  __syncthreads();

  // phase 4b: wave 0 -> te, wave 1 -> ve (same accumulation order as before)
  if (w == 0){
    float m0 = smask[0], m1 = smask[1], m2 = smask[2];
    float4 te[3]; float ss = 0.f;
    #pragma unroll
    for (int q = 0; q < 3; ++q){
      float4 t1v = ((const float4*)st1)[lane + q * 64];
      float4 a0 = ((const float4*)&sa[0][0])[lane + q * 64];
      float4 a1 = ((const float4*)&sa[1][0])[lane + q * 64];
      float4 a2 = ((const float4*)&sa[2][0])[lane + q * 64];
      float4 t;
      t.x = ((t1v.x + m0 * a0.x) + m1 * a1.x) + m2 * a2.x;
      t.y = ((t1v.y + m0 * a0.y) + m1 * a1.y) + m2 * a2.y;
      t.z = ((t1v.z + m0 * a0.z) + m1 * a1.z) + m2 * a2.z;
      t.w = ((t1v.w + m0 * a0.w) + m1 * a1.w) + m2 * a2.w;
      te[q] = t;
      ss += t.x * t.x + t.y * t.y + t.z * t.z + t.w * t.w;
    }
    ss = wsum(ss);
    float inv = 1.0f / fmaxf(sqrtf(ss), 1e-12f);
    #pragma unroll
    for (int q = 0; q < 3; ++q){
      float4 x = {te[q].x * inv, te[q].y * inv, te[q].z * inv, te[q].w * inv};
      store_bf16x4(tenb + (size_t)i * DD + lane * 4 + q * 256, x);
    }
  } else if (w == 1){
    float m0 = smask[0], m1 = smask[1], m2 = smask[2];
    int b0 = sbi[0], b1 = sbi[1], b2 = sbi[2];
    float4 ve[3]; float ss = 0.f;
    #pragma unroll
    for (int q = 0; q < 3; ++q){
      float4 w0 = ((const float4*)&so[b0][0])[lane + q * 64];
      float4 w1 = ((const float4*)&so[b1][0])[lane + q * 64];
      float4 w2 = ((const float4*)&so[b2][0])[lane + q * 64];
      float4 t;
      t.x = ((m0 * w0.x + m1 * w1.x)) + m2 * w2.x;
      t.y = ((m0 * w0.y + m1 * w1.y)) + m2 * w2.y;
      t.z = ((m0 * w0.z + m1 * w1.z)) + m2 * w2.z;
      t.w = ((m0 * w0.w + m1 * w1.w)) + m2 * w2.w;
      ve[q] = t;
      ss += t.x * t.x + t.y * t.y + t.z * t.z + t.w * t.w;
    }
    ss = wsum(ss);
    float inv = 1.0f / fmaxf(sqrtf(ss), 1e-12f);
    #pragma unroll
    for (int q = 0; q < 3; ++q){
      float4 x = {ve[q].x * inv, ve[q].y * inv, ve[q].z * inv, ve[q].w * inv};
      store_bf16x4(venb + (size_t)i * DD + lane * 4 + q * 256, x);
    }
  }
}

// ====== unified GEMM kernel: blocks [0,nec) = ec (bf16), rest = wpg (i8) ======
// (frozen r11 best-measured config)
#define MFMAI8(d, av, bv) d = __builtin_amdgcn_mfma_i32_16x16x64_i8(av, bv, d, 0, 0, 0)

__global__ __launch_bounds__(256, 3) void gemms_fused(
    const int8_t* __restrict__ A, const int8_t* __restrict__ B,
    float* __restrict__ sumexp,
    const __hip_bfloat16* __restrict__ ten, const __hip_bfloat16* __restrict__ ven,
    float* __restrict__ rowsum, float* __restrict__ colsum, float* __restrict__ Ldiag,
    int nec, int necx)
{
  __shared__ char lds[49152];
  const int tid = threadIdx.x;
  const int lane = tid & 63, wid = tid >> 6;

  if ((int)blockIdx.x < nec){
    // ---------------- ec path ----------------
    const int bx = blockIdx.x % necx, by = blockIdx.x / necx;
    __hip_bfloat16* As = (__hip_bfloat16*)lds;
    __hip_bfloat16* Bs = (__hip_bfloat16*)(lds + 8192);
    char* AsB = lds; char* BsB = lds + 8192;
    const int wr = wid >> 1, wc = wid & 1;
    f32x4 acc[4][4];
    #pragma unroll
    for (int i2 = 0; i2 < 4; ++i2)
      #pragma unroll
      for (int j = 0; j < 4; ++j) acc[i2][j] = (f32x4){0.f, 0.f, 0.f, 0.f};
    const char* Ab = (const char*)(ten + (size_t)(by * 128) * DD);
    const char* Bb = (const char*)(ven + (size_t)(bx * 128) * DD);
    const int srow = tid >> 2, scol = (tid & 3) * 16;
    const int r = lane & 15, kg = (lane >> 4) * 8;

    for (int kb = 0; kb < DD * 2; kb += 64){
      gload_lds16(Ab + (size_t)srow * (DD*2) + kb + scol, AsB + tid * 16);
      gload_lds16(Ab + (size_t)(srow + 64) * (DD*2) + kb + scol, AsB + 4096 + tid * 16);
      gload_lds16(Bb + (size_t)srow * (DD*2) + kb + scol, BsB + tid * 16);
      gload_lds16(Bb + (size_t)(srow + 64) * (DD*2) + kb + scol, BsB + 4096 + tid * 16);
      __syncthreads();
      bf16x8 af[4], bfr[4];
      #pragma unroll
      for (int mi = 0; mi < 4; ++mi)
        af[mi] = *(const bf16x8*)&As[(wr * 64 + mi * 16 + r) * 32 + kg];
      #pragma unroll
      for (int ni = 0; ni < 4; ++ni)
        bfr[ni] = *(const bf16x8*)&Bs[(wc * 64 + ni * 16 + r) * 32 + kg];
      #pragma unroll
      for (int mi = 0; mi < 4; ++mi)
        #pragma unroll
        for (int ni = 0; ni < 4; ++ni)
          acc[mi][ni] = __builtin_amdgcn_mfma_f32_16x16x32_bf16(af[mi], bfr[ni], acc[mi][ni], 0, 0, 0);
      __syncthreads();
    }
    int rowbase = by * 128 + wr * 64 + ((lane >> 4) << 2);
    float colacc[4] = {0.f, 0.f, 0.f, 0.f};
    #pragma unroll
    for (int mi = 0; mi < 4; ++mi){
      #pragma unroll
      for (int rr = 0; rr < 4; ++rr){
        float s = 0.f;
        #pragma unroll
        for (int ni = 0; ni < 4; ++ni){
          float e = expf(fmaf(acc[mi][ni][rr], TSCALE, -TSCALE));
          s += e; colacc[ni] += e;
        }
        s += __shfl_xor(s, 1, 64); s += __shfl_xor(s, 2, 64);
        s += __shfl_xor(s, 4, 64); s += __shfl_xor(s, 8, 64);
        if ((lane & 15) == 0) atomicAdd(&rowsum[rowbase + mi * 16 + rr], s);
      }
    }
    #pragma unroll
    for (int ni = 0; ni < 4; ++ni){
      float c = colacc[ni];
      c += __shfl_xor(c, 16, 64); c += __shfl_xor(c, 32, 64);
      if (lane < 16) atomicAdd(&colsum[bx * 128 + wc * 64 + ni * 16 + lane], c);
    }
    if (bx == by){
      #pragma unroll
      for (int mi = 0; mi < 4; ++mi)
        #pragma unroll
        for (int ni = 0; ni < 4; ++ni)
          #pragma unroll
          for (int rr = 0; rr < 4; ++rr){
            int grow = wr * 64 + mi * 16 + ((lane >> 4) << 2) + rr;
            int gcol = wc * 64 + ni * 16 + (lane & 15);
            if (grow == gcol) Ldiag[by * 128 + grow] = acc[mi][ni][rr] * TSCALE;
          }
    }
    return;
  }

  // ---------------- wpg path: i8 128x128, 3-buffer counted-vmcnt pipeline ----------------
  const int wr = wid >> 1, wc = wid & 1;      // 2x2 waves, 64x64 each
  const int r = lane & 15, kg = lane >> 4;

  int g = blockIdx.x - nec;                    // [0, 2400)
  int bx = (g & 7) * 10 + (g >> 3) % 10;       // 80 N-tiles, 10 per XCD-chunk
  int by = (g >> 3) / 10;                      // 30 M-tiles

  const int8_t* Abase = A + (size_t)by * 128 * DD;
  const int8_t* Bbase = B + (size_t)bx * 128 * DD;

  const int srow = tid >> 2, sc = tid & 3;     // srow 0..63
  const int ssw = ((sc ^ ((srow >> 1) & 3)) * 16);

  auto STAGE = [&](int p, int kt){
    gload_lds16(Abase + (size_t)srow * DD + kt * 64 + ssw, lds + p * 16384 + tid * 16);
    gload_lds16(Abase + (size_t)(64 + srow) * DD + kt * 64 + ssw, lds + p * 16384 + 4096 + tid * 16);
    gload_lds16(Bbase + (size_t)srow * DD + kt * 64 + ssw, lds + p * 16384 + 8192 + tid * 16);
    gload_lds16(Bbase + (size_t)(64 + srow) * DD + kt * 64 + ssw, lds + p * 16384 + 12288 + tid * 16);
  };
  auto LDA = [&](int p, int mi)->i32x4 {
    int row = wr * 64 + mi * 16 + r;
    return *(const i32x4*)(lds + p * 16384 + row * 64 + ((kg ^ ((row >> 1) & 3)) * 16));
  };
  auto LDB = [&](int p, int ni)->i32x4 {
    int row = wc * 64 + ni * 16 + r;
    return *(const i32x4*)(lds + p * 16384 + 8192 + row * 64 + ((kg ^ ((row >> 1) & 3)) * 16));
  };

  i32x4 acc[4][4];
  #pragma unroll
  for (int mi = 0; mi < 4; ++mi)
    #pragma unroll
    for (int ni = 0; ni < 4; ++ni) acc[mi][ni] = (i32x4){0, 0, 0, 0};

  STAGE(0, 0); STAGE(1, 1);    // 8 loads in flight per thread
  #pragma unroll
  for (int t = 0; t < 12; ++t){
    if (t < 11) asm volatile("s_waitcnt vmcnt(4)" ::: "memory");  // stage(t) landed
    else        asm volatile("s_waitcnt vmcnt(0)" ::: "memory");
    __builtin_amdgcn_s_barrier();
    __builtin_amdgcn_sched_barrier(0);
    if (t < 10) STAGE((t + 2) % 3, t + 2);
    const int p = t % 3;
    i32x4 af[4], bf[4];
    #pragma unroll
    for (int mi = 0; mi < 4; ++mi) af[mi] = LDA(p, mi);
    #pragma unroll
    for (int ni = 0; ni < 4; ++ni) bf[ni] = LDB(p, ni);
    __builtin_amdgcn_s_setprio(1);
    #pragma unroll
    for (int mi = 0; mi < 4; ++mi)
      #pragma unroll
      for (int ni = 0; ni < 4; ++ni) MFMAI8(acc[mi][ni], af[mi], bf[ni]);
    __builtin_amdgcn_s_setprio(0);
  }

  // epilogue: dequant + per-row sum of exp(logit-20)
  const float SC = TSCALE / 16129.0f;   // 20/127^2
  const int rowbase = by * 128 + wr * 64 + kg * 4;
  #pragma unroll
  for (int mi = 0; mi < 4; ++mi){
    #pragma unroll
    for (int rr = 0; rr < 4; ++rr){
      float s = 0.f;
      #pragma unroll
      for (int ni = 0; ni < 4; ++ni) s += expf(fmaf((float)acc[mi][ni][rr], SC, -TSCALE));
      s += __shfl_xor(s, 1, 64); s += __shfl_xor(s, 2, 64);
      s += __shfl_xor(s, 4, 64); s += __shfl_xor(s, 8, 64);
      if (r == 0) atomicAdd(&sumexp[rowbase + mi * 16 + rr], s);
    }
  }
}

__global__ __launch_bounds__(256) void finalize_kernel(
    const float* __restrict__ sumexp, const float* __restrict__ diagmax,
    const float* __restrict__ rowsum, const float* __restrict__ colsum,
    const float* __restrict__ Ldiag, const float* __restrict__ lossv_arr,
    float* __restrict__ out, int NB)
{
  int tid = threadIdx.x;
  float p = 0.f;
  for (int r = tid; r < 3 * NB; r += 256) p += logf(sumexp[r]) + TSCALE - diagmax[r];
  p *= (0.3f / (3.0f * NB));
  float q = 0.f, lv = 0.f;
  for (int i2 = tid; i2 < NB; i2 += 256){
    q += (logf(rowsum[i2]) + TSCALE - Ldiag[i2]) + (logf(colsum[i2]) + TSCALE - Ldiag[i2]);
    lv += lossv_arr[i2];
  }
  p += q * (0.25f / NB) + lv * (0.2f / NB);
  __shared__ float red[256];
  red[tid] = p; __syncthreads();
  for (int s = 128; s > 0; s >>= 1){ if (tid < s) red[tid] += red[tid + s]; __syncthreads(); }
  if (tid == 0) out[0] = red[0];
}

extern "C" void kernel_launch(void* const* d_in, const int* in_sizes, int n_in,
                              void* d_out, int out_size, void* d_ws, size_t ws_size,
                              hipStream_t stream) {
  const float* obj = (const float*)d_in[0];
  const float* txt = (const float*)d_in[1];
  const float* mdl = (const float*)d_in[2];
  const int*   lab = (const int*)d_in[3];

  const int NB = in_sizes[1] / (4 * DD);   // 1280
  const int C  = in_sizes[2] / NB;          // 504

  float* ws = (float*)d_ws;
  size_t o = 0;
  int8_t* obji8 = (int8_t*)(ws + o); o += (size_t)NB * 8 * DD / 4;   // bytes/4
  int8_t* argi8 = (int8_t*)(ws + o); o += (size_t)NB * 3 * DD / 4;
  __hip_bfloat16* tenb = (__hip_bfloat16*)(ws + o); o += (size_t)NB * DD / 2;
  __hip_bfloat16* venb = (__hip_bfloat16*)(ws + o); o += (size_t)NB * DD / 2;
  float* diagmax = ws + o; o += (size_t)3 * NB;
  float* Ldiag = ws + o; o += (size_t)NB;
  float* lossv_arr = ws + o; o += (size_t)NB;
  float* zr = ws + o;
  float* sumexp = zr;                      // 3*NB
  float* rowsum = zr + 3 * NB;             // NB
  float* colsum = rowsum + NB;             // NB

  diag_teve<<<NB, 512, 0, stream>>>(obj, txt, mdl, lab, diagmax, obji8, argi8,
                                    tenb, venb, lossv_arr, zr, C);
  const int necx = NB / 128;               // 10
  const int nec = necx * necx;             // 100 ec blocks
  const int nwpg = (NB * 3 / 128) * (NB * 8 / 128);   // 2400 wpg blocks
  gemms_fused<<<nec + nwpg, 256, 0, stream>>>(argi8, obji8, sumexp, tenb, venb,
                                              rowsum, colsum, Ldiag, nec, necx);
  finalize_kernel<<<1, 256, 0, stream>>>(sumexp, diagmax, rowsum, colsum, Ldiag, lossv_arr,
                                         (float*)d_out, NB);
}

// Round 16
// 90.420 us; speedup vs baseline: 1.5022x; 1.1296x over previous
//
#include <hip/hip_runtime.h>
#include <hip/hip_bf16.h>
#include <cstdint>
#include <cstddef>

#define DD 768
#define TSCALE 20.0f

typedef short bf16x8 __attribute__((ext_vector_type(8)));
typedef float f32x4 __attribute__((ext_vector_type(4)));
typedef int   i32x4 __attribute__((ext_vector_type(4)));

__device__ inline float wsum(float v){
  #pragma unroll
  for (int m = 1; m < 64; m <<= 1) v += __shfl_xor(v, m, 64);
  return v;
}
__device__ inline float wmax(float v){
  #pragma unroll
  for (int m = 1; m < 64; m <<= 1) v = fmaxf(v, __shfl_xor(v, m, 64));
  return v;
}

__device__ inline void gload_lds16(const void* g, void* l){
  __builtin_amdgcn_global_load_lds(
      (const __attribute__((address_space(1))) uint32_t*)g,
      (__attribute__((address_space(3))) uint32_t*)l, 16, 0, 0);
}

__device__ inline void store_bf16x4(__hip_bfloat16* p, float4 x){
  __hip_bfloat16 t[4] = {__float2bfloat16(x.x), __float2bfloat16(x.y),
                         __float2bfloat16(x.z), __float2bfloat16(x.w)};
  *(ushort4*)p = *(const ushort4*)t;
}

// quantize 4 normalized floats (|x|<=1) to int8 at scale 127, packed store
__device__ inline void store_i8x4(int8_t* p, float4 x){
  int q0 = __float2int_rn(x.x * 127.f), q1 = __float2int_rn(x.y * 127.f);
  int q2 = __float2int_rn(x.z * 127.f), q3 = __float2int_rn(x.w * 127.f);
  uint32_t w = (uint32_t)(uint8_t)(int8_t)q0 | ((uint32_t)(uint8_t)(int8_t)q1 << 8) |
               ((uint32_t)(uint8_t)(int8_t)q2 << 16) | ((uint32_t)(uint8_t)(int8_t)q3 << 24);
  *(uint32_t*)p = w;
}

// ====== fused normalize + diag argmax/mask + te/ve + i8 emit + lossv, 8 waves ======
// (r15 structure: parallel phase-3 dots, launch_bounds(512,2).)
__global__ __launch_bounds__(512, 2) void diag_teve(
    const float* __restrict__ obj, const float* __restrict__ txt,
    const float* __restrict__ mdl, const int* __restrict__ lab,
    float* __restrict__ diagmax,
    int8_t* __restrict__ obji8, int8_t* __restrict__ argi8,
    __hip_bfloat16* __restrict__ tenb, __hip_bfloat16* __restrict__ venb,
    float* __restrict__ lossv_arr, float* __restrict__ zr, int C)
{
  __shared__ float so[8][DD];
  __shared__ float sa[3][DD];
  __shared__ float st1[DD];
  __shared__ float sdot[3][8];
  __shared__ float smask[3];
  __shared__ int   sbi[3];
  __shared__ float pmax[4], psum[4];

  const int i = blockIdx.x, tid = threadIdx.x;
  const int lane = tid & 63, w = tid >> 6;

  if (tid < 5) zr[i * 5 + tid] = 0.f;

  // phase 1: wave w normalizes obj row w
  {
    const float* src = obj + ((size_t)i * 8 + w) * DD;
    float4 v[3]; float ss = 0.f;
    #pragma unroll
    for (int q = 0; q < 3; ++q){
      v[q] = ((const float4*)src)[lane + q * 64];
      ss += v[q].x * v[q].x + v[q].y * v[q].y + v[q].z * v[q].z + v[q].w * v[q].w;
    }
    ss = wsum(ss);
    float inv = 1.0f / fmaxf(sqrtf(ss), 1e-12f);
    #pragma unroll
    for (int q = 0; q < 3; ++q){
      float4 x = {v[q].x * inv, v[q].y * inv, v[q].z * inv, v[q].w * inv};
      ((float4*)&so[w][0])[lane + q * 64] = x;
      store_i8x4(obji8 + ((size_t)i * 8 + w) * DD + 4 * (lane + q * 64), x);
    }
  }

  // phase 2: waves 0-2 normalize arg j=w; wave 3 t1; waves 4-7 lossv partials
  if (w < 4){
    int s4 = (w == 0) ? 0 : ((w < 3) ? (w + 1) : 1);
    const float* ap = txt + ((size_t)i * 4 + s4) * DD;
    float4 a[3]; float ss = 0.f;
    #pragma unroll
    for (int q = 0; q < 3; ++q){
      a[q] = ((const float4*)ap)[lane + q * 64];
      ss += a[q].x * a[q].x + a[q].y * a[q].y + a[q].z * a[q].z + a[q].w * a[q].w;
    }
    ss = wsum(ss);
    float inv = 1.0f / fmaxf(sqrtf(ss), 1e-12f);
    #pragma unroll
    for (int q = 0; q < 3; ++q){
      a[q].x *= inv; a[q].y *= inv; a[q].z *= inv; a[q].w *= inv;
    }
    if (w < 3){
      #pragma unroll
      for (int q = 0; q < 3; ++q){
        ((float4*)&sa[w][0])[lane + q * 64] = a[q];
        store_i8x4(argi8 + (size_t)(i * 3 + w) * DD + 4 * (lane + q * 64), a[q]);
      }
    } else {
      #pragma unroll
      for (int q = 0; q < 3; ++q) ((float4*)st1)[lane + q * 64] = a[q];
    }
  } else {
    const int W = w - 4;
    const float* x = mdl + (size_t)i * C;
    float mx = -3.0e38f;
    for (int c = lane + W * 64; c < C; c += 256) mx = fmaxf(mx, x[c]);
    mx = wmax(mx);
    float s = 0.f;
    for (int c = lane + W * 64; c < C; c += 256) s += expf(x[c] - mx);
    s = wsum(s);
    if (lane == 0){ pmax[W] = mx; psum[W] = s; }
  }
  __syncthreads();

  // phase 3 (parallel): wave w computes dot(sa[j], so[w]) j=0..2; wave 3 lossv
  {
    float4 v[3];
    #pragma unroll
    for (int q = 0; q < 3; ++q) v[q] = ((const float4*)&so[w][0])[lane + q * 64];
    #pragma unroll
    for (int j = 0; j < 3; ++j){
      float s = 0.f;
      #pragma unroll
      for (int q = 0; q < 3; ++q){
        float4 aq = ((const float4*)&sa[j][0])[lane + q * 64];
        s += aq.x * v[q].x + aq.y * v[q].y + aq.z * v[q].z + aq.w * v[q].w;
      }
      s = wsum(s);
      if (lane == 0) sdot[j][w] = s;
    }
    if (w == 3 && lane == 0){
      float M = fmaxf(fmaxf(pmax[0], pmax[1]), fmaxf(pmax[2], pmax[3]));
      float S = psum[0] * expf(pmax[0] - M) + psum[1] * expf(pmax[1] - M)
              + psum[2] * expf(pmax[2] - M) + psum[3] * expf(pmax[3] - M);
      lossv_arr[i] = logf(S) + M - mdl[(size_t)i * C + lab[i]];
    }
  }
  __syncthreads();

  // phase 4a: wave-0 lanes 0-2: 8-way argmax, strict > (first-index ties)
  if (w == 0 && lane < 3){
    float best = -3.0e38f; int bi = 0;
    #pragma unroll
    for (int k = 0; k < 8; ++k){
      float s = sdot[lane][k];
      if (s > best){ best = s; bi = k; }
    }
    float dm = best * TSCALE;
    diagmax[i * 3 + lane] = dm;
    smask[lane] = (dm > 1.0f) ? 1.0f : 0.0f;
    sbi[lane] = bi;
  }
  __syncthreads();

  // phase 4b: wave 0 -> te, wave 1 -> ve
  if (w == 0){
    float m0 = smask[0], m1 = smask[1], m2 = smask[2];
    float4 te[3]; float ss = 0.f;
    #pragma unroll
    for (int q = 0; q < 3; ++q){
      float4 t1v = ((const float4*)st1)[lane + q * 64];
      float4 a0 = ((const float4*)&sa[0][0])[lane + q * 64];
      float4 a1 = ((const float4*)&sa[1][0])[lane + q * 64];
      float4 a2 = ((const float4*)&sa[2][0])[lane + q * 64];
      float4 t;
      t.x = ((t1v.x + m0 * a0.x) + m1 * a1.x) + m2 * a2.x;
      t.y = ((t1v.y + m0 * a0.y) + m1 * a1.y) + m2 * a2.y;
      t.z = ((t1v.z + m0 * a0.z) + m1 * a1.z) + m2 * a2.z;
      t.w = ((t1v.w + m0 * a0.w) + m1 * a1.w) + m2 * a2.w;
      te[q] = t;
      ss += t.x * t.x + t.y * t.y + t.z * t.z + t.w * t.w;
    }
    ss = wsum(ss);
    float inv = 1.0f / fmaxf(sqrtf(ss), 1e-12f);
    #pragma unroll
    for (int q = 0; q < 3; ++q){
      float4 x = {te[q].x * inv, te[q].y * inv, te[q].z * inv, te[q].w * inv};
      store_bf16x4(tenb + (size_t)i * DD + lane * 4 + q * 256, x);
    }
  } else if (w == 1){
    float m0 = smask[0], m1 = smask[1], m2 = smask[2];
    int b0 = sbi[0], b1 = sbi[1], b2 = sbi[2];
    float4 ve[3]; float ss = 0.f;
    #pragma unroll
    for (int q = 0; q < 3; ++q){
      float4 w0 = ((const float4*)&so[b0][0])[lane + q * 64];
      float4 w1 = ((const float4*)&so[b1][0])[lane + q * 64];
      float4 w2 = ((const float4*)&so[b2][0])[lane + q * 64];
      float4 t;
      t.x = ((m0 * w0.x + m1 * w1.x)) + m2 * w2.x;
      t.y = ((m0 * w0.y + m1 * w1.y)) + m2 * w2.y;
      t.z = ((m0 * w0.z + m1 * w1.z)) + m2 * w2.z;
      t.w = ((m0 * w0.w + m1 * w1.w)) + m2 * w2.w;
      ve[q] = t;
      ss += t.x * t.x + t.y * t.y + t.z * t.z + t.w * t.w;
    }
    ss = wsum(ss);
    float inv = 1.0f / fmaxf(sqrtf(ss), 1e-12f);
    #pragma unroll
    for (int q = 0; q < 3; ++q){
      float4 x = {ve[q].x * inv, ve[q].y * inv, ve[q].z * inv, ve[q].w * inv};
      store_bf16x4(venb + (size_t)i * DD + lane * 4 + q * 256, x);
    }
  }
}

// ====== unified GEMM kernel: blocks [0,nec) = ec (bf16), rest = wpg (i8) ======
// wpg NEW: 128x256 block, 4 waves each 64x128 (acc[4][8]), BK=64B, 2-buffer
// 48KB LDS, 2 blocks/CU. Per tile: vmcnt(0)[stage t] -> barrier -> issue
// stage(t+1) -> ds_reads -> 32 MFMA. Doubles per-barrier MFMA density vs r11.
#define MFMAI8(d, av, bv) d = __builtin_amdgcn_mfma_i32_16x16x64_i8(av, bv, d, 0, 0, 0)

__global__ __launch_bounds__(256, 2) void gemms_fused(
    const int8_t* __restrict__ A, const int8_t* __restrict__ B,
    float* __restrict__ sumexp,
    const __hip_bfloat16* __restrict__ ten, const __hip_bfloat16* __restrict__ ven,
    float* __restrict__ rowsum, float* __restrict__ colsum, float* __restrict__ Ldiag,
    int nec, int necx)
{
  __shared__ char lds[49152];
  const int tid = threadIdx.x;
  const int lane = tid & 63, wid = tid >> 6;

  if ((int)blockIdx.x < nec){
    // ---------------- ec path (unchanged) ----------------
    const int bx = blockIdx.x % necx, by = blockIdx.x / necx;
    __hip_bfloat16* As = (__hip_bfloat16*)lds;
    __hip_bfloat16* Bs = (__hip_bfloat16*)(lds + 8192);
    char* AsB = lds; char* BsB = lds + 8192;
    const int wr = wid >> 1, wc = wid & 1;
    f32x4 acc[4][4];
    #pragma unroll
    for (int i2 = 0; i2 < 4; ++i2)
      #pragma unroll
      for (int j = 0; j < 4; ++j) acc[i2][j] = (f32x4){0.f, 0.f, 0.f, 0.f};
    const char* Ab = (const char*)(ten + (size_t)(by * 128) * DD);
    const char* Bb = (const char*)(ven + (size_t)(bx * 128) * DD);
    const int srow = tid >> 2, scol = (tid & 3) * 16;
    const int r = lane & 15, kg = (lane >> 4) * 8;

    for (int kb = 0; kb < DD * 2; kb += 64){
      gload_lds16(Ab + (size_t)srow * (DD*2) + kb + scol, AsB + tid * 16);
      gload_lds16(Ab + (size_t)(srow + 64) * (DD*2) + kb + scol, AsB + 4096 + tid * 16);
      gload_lds16(Bb + (size_t)srow * (DD*2) + kb + scol, BsB + tid * 16);
      gload_lds16(Bb + (size_t)(srow + 64) * (DD*2) + kb + scol, BsB + 4096 + tid * 16);
      __syncthreads();
      bf16x8 af[4], bfr[4];
      #pragma unroll
      for (int mi = 0; mi < 4; ++mi)
        af[mi] = *(const bf16x8*)&As[(wr * 64 + mi * 16 + r) * 32 + kg];
      #pragma unroll
      for (int ni = 0; ni < 4; ++ni)
        bfr[ni] = *(const bf16x8*)&Bs[(wc * 64 + ni * 16 + r) * 32 + kg];
      #pragma unroll
      for (int mi = 0; mi < 4; ++mi)
        #pragma unroll
        for (int ni = 0; ni < 4; ++ni)
          acc[mi][ni] = __builtin_amdgcn_mfma_f32_16x16x32_bf16(af[mi], bfr[ni], acc[mi][ni], 0, 0, 0);
      __syncthreads();
    }
    int rowbase = by * 128 + wr * 64 + ((lane >> 4) << 2);
    float colacc[4] = {0.f, 0.f, 0.f, 0.f};
    #pragma unroll
    for (int mi = 0; mi < 4; ++mi){
      #pragma unroll
      for (int rr = 0; rr < 4; ++rr){
        float s = 0.f;
        #pragma unroll
        for (int ni = 0; ni < 4; ++ni){
          float e = expf(fmaf(acc[mi][ni][rr], TSCALE, -TSCALE));
          s += e; colacc[ni] += e;
        }
        s += __shfl_xor(s, 1, 64); s += __shfl_xor(s, 2, 64);
        s += __shfl_xor(s, 4, 64); s += __shfl_xor(s, 8, 64);
        if ((lane & 15) == 0) atomicAdd(&rowsum[rowbase + mi * 16 + rr], s);
      }
    }
    #pragma unroll
    for (int ni = 0; ni < 4; ++ni){
      float c = colacc[ni];
      c += __shfl_xor(c, 16, 64); c += __shfl_xor(c, 32, 64);
      if (lane < 16) atomicAdd(&colsum[bx * 128 + wc * 64 + ni * 16 + lane], c);
    }
    if (bx == by){
      #pragma unroll
      for (int mi = 0; mi < 4; ++mi)
        #pragma unroll
        for (int ni = 0; ni < 4; ++ni)
          #pragma unroll
          for (int rr = 0; rr < 4; ++rr){
            int grow = wr * 64 + mi * 16 + ((lane >> 4) << 2) + rr;
            int gcol = wc * 64 + ni * 16 + (lane & 15);
            if (grow == gcol) Ldiag[by * 128 + grow] = acc[mi][ni][rr] * TSCALE;
          }
    }
    return;
  }

  // -------- wpg path: i8 128x256 block, 64x128/wave, 2-buffer counted pipeline --------
  const int wr = wid >> 1, wc = wid & 1;      // 2x2 waves: 64 M x 128 N each
  const int r = lane & 15, kg = lane >> 4;

  int g = blockIdx.x - nec;                    // [0, 1200)
  int bx = (g & 7) * 5 + (g >> 3) % 5;         // 40 N-tiles (256 cols), 5 per XCD
  int by = (g >> 3) / 5;                       // 30 M-tiles (128 rows)

  const int8_t* Abase = A + (size_t)by * 128 * DD;
  const int8_t* Bbase = B + (size_t)bx * 256 * DD;

  auto STAGE = [&](int p, int kt){
    // A: 128 rows x 4 chunks = 512 chunk-loads (2/thread)
    #pragma unroll
    for (int j = 0; j < 2; ++j){
      int c = j * 256 + tid;
      int row = c >> 2, cc = c & 3;
      int cc2 = cc ^ ((row >> 1) & 3);
      gload_lds16(Abase + (size_t)row * DD + kt * 64 + cc2 * 16,
                  lds + p * 24576 + c * 16);
    }
    // B: 256 rows x 4 chunks = 1024 chunk-loads (4/thread)
    #pragma unroll
    for (int j = 0; j < 4; ++j){
      int c = j * 256 + tid;
      int row = c >> 2, cc = c & 3;
      int cc2 = cc ^ ((row >> 1) & 3);
      gload_lds16(Bbase + (size_t)row * DD + kt * 64 + cc2 * 16,
                  lds + p * 24576 + 8192 + c * 16);
    }
  };
  auto LDA = [&](int p, int mi)->i32x4 {
    int row = wr * 64 + mi * 16 + r;
    return *(const i32x4*)(lds + p * 24576 + row * 64 + ((kg ^ ((row >> 1) & 3)) * 16));
  };
  auto LDB = [&](int p, int ni)->i32x4 {
    int row = wc * 128 + ni * 16 + r;
    return *(const i32x4*)(lds + p * 24576 + 8192 + row * 64 + ((kg ^ ((row >> 1) & 3)) * 16));
  };

  i32x4 acc[4][8];
  #pragma unroll
  for (int mi = 0; mi < 4; ++mi)
    #pragma unroll
    for (int ni = 0; ni < 8; ++ni) acc[mi][ni] = (i32x4){0, 0, 0, 0};

  STAGE(0, 0);
  #pragma unroll
  for (int t = 0; t < 12; ++t){
    asm volatile("s_waitcnt vmcnt(0)" ::: "memory");   // stage(t) landed (only group in flight)
    __builtin_amdgcn_s_barrier();
    __builtin_amdgcn_sched_barrier(0);
    const int p = t & 1;
    if (t < 11) STAGE(p ^ 1, t + 1);                    // other buf: prior readers retired
    i32x4 af[4], bf[8];
    #pragma unroll
    for (int mi = 0; mi < 4; ++mi) af[mi] = LDA(p, mi);
    #pragma unroll
    for (int ni = 0; ni < 8; ++ni) bf[ni] = LDB(p, ni);
    __builtin_amdgcn_s_setprio(1);
    #pragma unroll
    for (int mi = 0; mi < 4; ++mi)
      #pragma unroll
      for (int ni = 0; ni < 8; ++ni) MFMAI8(acc[mi][ni], af[mi], bf[ni]);
    __builtin_amdgcn_s_setprio(0);
  }

  // epilogue: dequant + per-row sum of exp(logit-20). row = by*128 + wr*64 + mi*16 + kg*4 + rr.
  const float SC = TSCALE / 16129.0f;   // 20/127^2
  const int rowbase = by * 128 + wr * 64 + kg * 4;
  #pragma unroll
  for (int mi = 0; mi < 4; ++mi){
    #pragma unroll
    for (int rr = 0; rr < 4; ++rr){
      float s = 0.f;
      #pragma unroll
      for (int ni = 0; ni < 8; ++ni) s += expf(fmaf((float)acc[mi][ni][rr], SC, -TSCALE));
      s += __shfl_xor(s, 1, 64); s += __shfl_xor(s, 2, 64);
      s += __shfl_xor(s, 4, 64); s += __shfl_xor(s, 8, 64);
      if (r == 0) atomicAdd(&sumexp[rowbase + mi * 16 + rr], s);
    }
  }
}

__global__ __launch_bounds__(256) void finalize_kernel(
    const float* __restrict__ sumexp, const float* __restrict__ diagmax,
    const float* __restrict__ rowsum, const float* __restrict__ colsum,
    const float* __restrict__ Ldiag, const float* __restrict__ lossv_arr,
    float* __restrict__ out, int NB)
{
  int tid = threadIdx.x;
  float p = 0.f;
  for (int r = tid; r < 3 * NB; r += 256) p += logf(sumexp[r]) + TSCALE - diagmax[r];
  p *= (0.3f / (3.0f * NB));
  float q = 0.f, lv = 0.f;
  for (int i2 = tid; i2 < NB; i2 += 256){
    q += (logf(rowsum[i2]) + TSCALE - Ldiag[i2]) + (logf(colsum[i2]) + TSCALE - Ldiag[i2]);
    lv += lossv_arr[i2];
  }
  p += q * (0.25f / NB) + lv * (0.2f / NB);
  __shared__ float red[256];
  red[tid] = p; __syncthreads();
  for (int s = 128; s > 0; s >>= 1){ if (tid < s) red[tid] += red[tid + s]; __syncthreads(); }
  if (tid == 0) out[0] = red[0];
}

extern "C" void kernel_launch(void* const* d_in, const int* in_sizes, int n_in,
                              void* d_out, int out_size, void* d_ws, size_t ws_size,
                              hipStream_t stream) {
  const float* obj = (const float*)d_in[0];
  const float* txt = (const float*)d_in[1];
  const float* mdl = (const float*)d_in[2];
  const int*   lab = (const int*)d_in[3];

  const int NB = in_sizes[1] / (4 * DD);   // 1280
  const int C  = in_sizes[2] / NB;          // 504

  float* ws = (float*)d_ws;
  size_t o = 0;
  int8_t* obji8 = (int8_t*)(ws + o); o += (size_t)NB * 8 * DD / 4;   // bytes/4
  int8_t* argi8 = (int8_t*)(ws + o); o += (size_t)NB * 3 * DD / 4;
  __hip_bfloat16* tenb = (__hip_bfloat16*)(ws + o); o += (size_t)NB * DD / 2;
  __hip_bfloat16* venb = (__hip_bfloat16*)(ws + o); o += (size_t)NB * DD / 2;
  float* diagmax = ws + o; o += (size_t)3 * NB;
  float* Ldiag = ws + o; o += (size_t)NB;
  float* lossv_arr = ws + o; o += (size_t)NB;
  float* zr = ws + o;
  float* sumexp = zr;                      // 3*NB
  float* rowsum = zr + 3 * NB;             // NB
  float* colsum = rowsum + NB;             // NB

  diag_teve<<<NB, 512, 0, stream>>>(obj, txt, mdl, lab, diagmax, obji8, argi8,
                                    tenb, venb, lossv_arr, zr, C);
  const int necx = NB / 128;               // 10
  const int nec = necx * necx;             // 100 ec blocks
  const int nwpg = (NB * 3 / 128) * (NB * 8 / 256);   // 30 x 40 = 1200 wpg blocks
  gemms_fused<<<nec + nwpg, 256, 0, stream>>>(argi8, obji8, sumexp, tenb, venb,
                                              rowsum, colsum, Ldiag, nec, necx);
  finalize_kernel<<<1, 256, 0, stream>>>(sumexp, diagmax, rowsum, colsum, Ldiag, lossv_arr,
                                         (float*)d_out, NB);
}

// Round 17
// 88.539 us; speedup vs baseline: 1.5341x; 1.0212x over previous
//
#include <hip/hip_runtime.h>
#include <hip/hip_bf16.h>
#include <cstdint>
#include <cstddef>

#define DD 768
#define TSCALE 20.0f

typedef short bf16x8 __attribute__((ext_vector_type(8)));
typedef float f32x4 __attribute__((ext_vector_type(4)));
typedef int   i32x4 __attribute__((ext_vector_type(4)));

__device__ inline float wsum(float v){
  #pragma unroll
  for (int m = 1; m < 64; m <<= 1) v += __shfl_xor(v, m, 64);
  return v;
}
__device__ inline float wmax(float v){
  #pragma unroll
  for (int m = 1; m < 64; m <<= 1) v = fmaxf(v, __shfl_xor(v, m, 64));
  return v;
}

__device__ inline void gload_lds16(const void* g, void* l){
  __builtin_amdgcn_global_load_lds(
      (const __attribute__((address_space(1))) uint32_t*)g,
      (__attribute__((address_space(3))) uint32_t*)l, 16, 0, 0);
}

__device__ inline void store_bf16x4(__hip_bfloat16* p, float4 x){
  __hip_bfloat16 t[4] = {__float2bfloat16(x.x), __float2bfloat16(x.y),
                         __float2bfloat16(x.z), __float2bfloat16(x.w)};
  *(ushort4*)p = *(const ushort4*)t;
}

// quantize 4 normalized floats (|x|<=1) to int8 at scale 127, packed store
__device__ inline void store_i8x4(int8_t* p, float4 x){
  int q0 = __float2int_rn(x.x * 127.f), q1 = __float2int_rn(x.y * 127.f);
  int q2 = __float2int_rn(x.z * 127.f), q3 = __float2int_rn(x.w * 127.f);
  uint32_t w = (uint32_t)(uint8_t)(int8_t)q0 | ((uint32_t)(uint8_t)(int8_t)q1 << 8) |
               ((uint32_t)(uint8_t)(int8_t)q2 << 16) | ((uint32_t)(uint8_t)(int8_t)q3 << 24);
  *(uint32_t*)p = w;
}

// ====== fused normalize + diag argmax/mask + te/ve + i8 emit + lossv, 8 waves ======
// (r15 structure: parallel phase-3 dots, launch_bounds(512,2).)
__global__ __launch_bounds__(512, 2) void diag_teve(
    const float* __restrict__ obj, const float* __restrict__ txt,
    const float* __restrict__ mdl, const int* __restrict__ lab,
    float* __restrict__ diagmax,
    int8_t* __restrict__ obji8, int8_t* __restrict__ argi8,
    __hip_bfloat16* __restrict__ tenb, __hip_bfloat16* __restrict__ venb,
    float* __restrict__ lossv_arr, float* __restrict__ zr, int C)
{
  __shared__ float so[8][DD];
  __shared__ float sa[3][DD];
  __shared__ float st1[DD];
  __shared__ float sdot[3][8];
  __shared__ float smask[3];
  __shared__ int   sbi[3];
  __shared__ float pmax[4], psum[4];

  const int i = blockIdx.x, tid = threadIdx.x;
  const int lane = tid & 63, w = tid >> 6;

  if (tid < 5) zr[i * 5 + tid] = 0.f;

  // phase 1: wave w normalizes obj row w
  {
    const float* src = obj + ((size_t)i * 8 + w) * DD;
    float4 v[3]; float ss = 0.f;
    #pragma unroll
    for (int q = 0; q < 3; ++q){
      v[q] = ((const float4*)src)[lane + q * 64];
      ss += v[q].x * v[q].x + v[q].y * v[q].y + v[q].z * v[q].z + v[q].w * v[q].w;
    }
    ss = wsum(ss);
    float inv = 1.0f / fmaxf(sqrtf(ss), 1e-12f);
    #pragma unroll
    for (int q = 0; q < 3; ++q){
      float4 x = {v[q].x * inv, v[q].y * inv, v[q].z * inv, v[q].w * inv};
      ((float4*)&so[w][0])[lane + q * 64] = x;
      store_i8x4(obji8 + ((size_t)i * 8 + w) * DD + 4 * (lane + q * 64), x);
    }
  }

  // phase 2: waves 0-2 normalize arg j=w; wave 3 t1; waves 4-7 lossv partials
  if (w < 4){
    int s4 = (w == 0) ? 0 : ((w < 3) ? (w + 1) : 1);
    const float* ap = txt + ((size_t)i * 4 + s4) * DD;
    float4 a[3]; float ss = 0.f;
    #pragma unroll
    for (int q = 0; q < 3; ++q){
      a[q] = ((const float4*)ap)[lane + q * 64];
      ss += a[q].x * a[q].x + a[q].y * a[q].y + a[q].z * a[q].z + a[q].w * a[q].w;
    }
    ss = wsum(ss);
    float inv = 1.0f / fmaxf(sqrtf(ss), 1e-12f);
    #pragma unroll
    for (int q = 0; q < 3; ++q){
      a[q].x *= inv; a[q].y *= inv; a[q].z *= inv; a[q].w *= inv;
    }
    if (w < 3){
      #pragma unroll
      for (int q = 0; q < 3; ++q){
        ((float4*)&sa[w][0])[lane + q * 64] = a[q];
        store_i8x4(argi8 + (size_t)(i * 3 + w) * DD + 4 * (lane + q * 64), a[q]);
      }
    } else {
      #pragma unroll
      for (int q = 0; q < 3; ++q) ((float4*)st1)[lane + q * 64] = a[q];
    }
  } else {
    const int W = w - 4;
    const float* x = mdl + (size_t)i * C;
    float mx = -3.0e38f;
    for (int c = lane + W * 64; c < C; c += 256) mx = fmaxf(mx, x[c]);
    mx = wmax(mx);
    float s = 0.f;
    for (int c = lane + W * 64; c < C; c += 256) s += expf(x[c] - mx);
    s = wsum(s);
    if (lane == 0){ pmax[W] = mx; psum[W] = s; }
  }
  __syncthreads();

  // phase 3 (parallel): wave w computes dot(sa[j], so[w]) j=0..2; wave 3 lossv
  {
    float4 v[3];
    #pragma unroll
    for (int q = 0; q < 3; ++q) v[q] = ((const float4*)&so[w][0])[lane + q * 64];
    #pragma unroll
    for (int j = 0; j < 3; ++j){
      float s = 0.f;
      #pragma unroll
      for (int q = 0; q < 3; ++q){
        float4 aq = ((const float4*)&sa[j][0])[lane + q * 64];
        s += aq.x * v[q].x + aq.y * v[q].y + aq.z * v[q].z + aq.w * v[q].w;
      }
      s = wsum(s);
      if (lane == 0) sdot[j][w] = s;
    }
    if (w == 3 && lane == 0){
      float M = fmaxf(fmaxf(pmax[0], pmax[1]), fmaxf(pmax[2], pmax[3]));
      float S = psum[0] * expf(pmax[0] - M) + psum[1] * expf(pmax[1] - M)
              + psum[2] * expf(pmax[2] - M) + psum[3] * expf(pmax[3] - M);
      lossv_arr[i] = logf(S) + M - mdl[(size_t)i * C + lab[i]];
    }
  }
  __syncthreads();

  // phase 4a: wave-0 lanes 0-2: 8-way argmax, strict > (first-index ties)
  if (w == 0 && lane < 3){
    float best = -3.0e38f; int bi = 0;
    #pragma unroll
    for (int k = 0; k < 8; ++k){
      float s = sdot[lane][k];
      if (s > best){ best = s; bi = k; }
    }
    float dm = best * TSCALE;
    diagmax[i * 3 + lane] = dm;
    smask[lane] = (dm > 1.0f) ? 1.0f : 0.0f;
    sbi[lane] = bi;
  }
  __syncthreads();

  // phase 4b: wave 0 -> te, wave 1 -> ve
  if (w == 0){
    float m0 = smask[0], m1 = smask[1], m2 = smask[2];
    float4 te[3]; float ss = 0.f;
    #pragma unroll
    for (int q = 0; q < 3; ++q){
      float4 t1v = ((const float4*)st1)[lane + q * 64];
      float4 a0 = ((const float4*)&sa[0][0])[lane + q * 64];
      float4 a1 = ((const float4*)&sa[1][0])[lane + q * 64];
      float4 a2 = ((const float4*)&sa[2][0])[lane + q * 64];
      float4 t;
      t.x = ((t1v.x + m0 * a0.x) + m1 * a1.x) + m2 * a2.x;
      t.y = ((t1v.y + m0 * a0.y) + m1 * a1.y) + m2 * a2.y;
      t.z = ((t1v.z + m0 * a0.z) + m1 * a1.z) + m2 * a2.z;
      t.w = ((t1v.w + m0 * a0.w) + m1 * a1.w) + m2 * a2.w;
      te[q] = t;
      ss += t.x * t.x + t.y * t.y + t.z * t.z + t.w * t.w;
    }
    ss = wsum(ss);
    float inv = 1.0f / fmaxf(sqrtf(ss), 1e-12f);
    #pragma unroll
    for (int q = 0; q < 3; ++q){
      float4 x = {te[q].x * inv, te[q].y * inv, te[q].z * inv, te[q].w * inv};
      store_bf16x4(tenb + (size_t)i * DD + lane * 4 + q * 256, x);
    }
  } else if (w == 1){
    float m0 = smask[0], m1 = smask[1], m2 = smask[2];
    int b0 = sbi[0], b1 = sbi[1], b2 = sbi[2];
    float4 ve[3]; float ss = 0.f;
    #pragma unroll
    for (int q = 0; q < 3; ++q){
      float4 w0 = ((const float4*)&so[b0][0])[lane + q * 64];
      float4 w1 = ((const float4*)&so[b1][0])[lane + q * 64];
      float4 w2 = ((const float4*)&so[b2][0])[lane + q * 64];
      float4 t;
      t.x = ((m0 * w0.x + m1 * w1.x)) + m2 * w2.x;
      t.y = ((m0 * w0.y + m1 * w1.y)) + m2 * w2.y;
      t.z = ((m0 * w0.z + m1 * w1.z)) + m2 * w2.z;
      t.w = ((m0 * w0.w + m1 * w1.w)) + m2 * w2.w;
      ve[q] = t;
      ss += t.x * t.x + t.y * t.y + t.z * t.z + t.w * t.w;
    }
    ss = wsum(ss);
    float inv = 1.0f / fmaxf(sqrtf(ss), 1e-12f);
    #pragma unroll
    for (int q = 0; q < 3; ++q){
      float4 x = {ve[q].x * inv, ve[q].y * inv, ve[q].z * inv, ve[q].w * inv};
      store_bf16x4(venb + (size_t)i * DD + lane * 4 + q * 256, x);
    }
  }
}

// ====== unified GEMM kernel: blocks [0,nec) = ec (bf16), rest = wpg (i8) ======
// wpg: 128x256 block, 4 waves each 64x128 (acc[4][8]), BK=64B, TRIPLE-buffered
// 72KB LDS (2 blocks/CU), counted vmcnt(6): stage t+2 issued at tile t; per tile
// wait completes stage t only — 2-tile latency window, no drain in the loop.
#define MFMAI8(d, av, bv) d = __builtin_amdgcn_mfma_i32_16x16x64_i8(av, bv, d, 0, 0, 0)

__global__ __launch_bounds__(256, 2) void gemms_fused(
    const int8_t* __restrict__ A, const int8_t* __restrict__ B,
    float* __restrict__ sumexp,
    const __hip_bfloat16* __restrict__ ten, const __hip_bfloat16* __restrict__ ven,
    float* __restrict__ rowsum, float* __restrict__ colsum, float* __restrict__ Ldiag,
    int nec, int necx)
{
  __shared__ char lds[73728];
  const int tid = threadIdx.x;
  const int lane = tid & 63, wid = tid >> 6;

  if ((int)blockIdx.x < nec){
    // ---------------- ec path (unchanged) ----------------
    const int bx = blockIdx.x % necx, by = blockIdx.x / necx;
    __hip_bfloat16* As = (__hip_bfloat16*)lds;
    __hip_bfloat16* Bs = (__hip_bfloat16*)(lds + 8192);
    char* AsB = lds; char* BsB = lds + 8192;
    const int wr = wid >> 1, wc = wid & 1;
    f32x4 acc[4][4];
    #pragma unroll
    for (int i2 = 0; i2 < 4; ++i2)
      #pragma unroll
      for (int j = 0; j < 4; ++j) acc[i2][j] = (f32x4){0.f, 0.f, 0.f, 0.f};
    const char* Ab = (const char*)(ten + (size_t)(by * 128) * DD);
    const char* Bb = (const char*)(ven + (size_t)(bx * 128) * DD);
    const int srow = tid >> 2, scol = (tid & 3) * 16;
    const int r = lane & 15, kg = (lane >> 4) * 8;

    for (int kb = 0; kb < DD * 2; kb += 64){
      gload_lds16(Ab + (size_t)srow * (DD*2) + kb + scol, AsB + tid * 16);
      gload_lds16(Ab + (size_t)(srow + 64) * (DD*2) + kb + scol, AsB + 4096 + tid * 16);
      gload_lds16(Bb + (size_t)srow * (DD*2) + kb + scol, BsB + tid * 16);
      gload_lds16(Bb + (size_t)(srow + 64) * (DD*2) + kb + scol, BsB + 4096 + tid * 16);
      __syncthreads();
      bf16x8 af[4], bfr[4];
      #pragma unroll
      for (int mi = 0; mi < 4; ++mi)
        af[mi] = *(const bf16x8*)&As[(wr * 64 + mi * 16 + r) * 32 + kg];
      #pragma unroll
      for (int ni = 0; ni < 4; ++ni)
        bfr[ni] = *(const bf16x8*)&Bs[(wc * 64 + ni * 16 + r) * 32 + kg];
      #pragma unroll
      for (int mi = 0; mi < 4; ++mi)
        #pragma unroll
        for (int ni = 0; ni < 4; ++ni)
          acc[mi][ni] = __builtin_amdgcn_mfma_f32_16x16x32_bf16(af[mi], bfr[ni], acc[mi][ni], 0, 0, 0);
      __syncthreads();
    }
    int rowbase = by * 128 + wr * 64 + ((lane >> 4) << 2);
    float colacc[4] = {0.f, 0.f, 0.f, 0.f};
    #pragma unroll
    for (int mi = 0; mi < 4; ++mi){
      #pragma unroll
      for (int rr = 0; rr < 4; ++rr){
        float s = 0.f;
        #pragma unroll
        for (int ni = 0; ni < 4; ++ni){
          float e = expf(fmaf(acc[mi][ni][rr], TSCALE, -TSCALE));
          s += e; colacc[ni] += e;
        }
        s += __shfl_xor(s, 1, 64); s += __shfl_xor(s, 2, 64);
        s += __shfl_xor(s, 4, 64); s += __shfl_xor(s, 8, 64);
        if ((lane & 15) == 0) atomicAdd(&rowsum[rowbase + mi * 16 + rr], s);
      }
    }
    #pragma unroll
    for (int ni = 0; ni < 4; ++ni){
      float c = colacc[ni];
      c += __shfl_xor(c, 16, 64); c += __shfl_xor(c, 32, 64);
      if (lane < 16) atomicAdd(&colsum[bx * 128 + wc * 64 + ni * 16 + lane], c);
    }
    if (bx == by){
      #pragma unroll
      for (int mi = 0; mi < 4; ++mi)
        #pragma unroll
        for (int ni = 0; ni < 4; ++ni)
          #pragma unroll
          for (int rr = 0; rr < 4; ++rr){
            int grow = wr * 64 + mi * 16 + ((lane >> 4) << 2) + rr;
            int gcol = wc * 64 + ni * 16 + (lane & 15);
            if (grow == gcol) Ldiag[by * 128 + grow] = acc[mi][ni][rr] * TSCALE;
          }
    }
    return;
  }

  // -------- wpg path: i8 128x256 block, 64x128/wave, 3-buffer counted pipeline --------
  const int wr = wid >> 1, wc = wid & 1;      // 2x2 waves: 64 M x 128 N each
  const int r = lane & 15, kg = lane >> 4;

  int g = blockIdx.x - nec;                    // [0, 1200)
  int bx = (g & 7) * 5 + (g >> 3) % 5;         // 40 N-tiles (256 cols), 5 per XCD
  int by = (g >> 3) / 5;                       // 30 M-tiles (128 rows)

  const int8_t* Abase = A + (size_t)by * 128 * DD;
  const int8_t* Bbase = B + (size_t)bx * 256 * DD;

  auto STAGE = [&](int p, int kt){
    // A: 128 rows x 4 chunks = 512 chunk-loads (2/thread)
    #pragma unroll
    for (int j = 0; j < 2; ++j){
      int c = j * 256 + tid;
      int row = c >> 2, cc = c & 3;
      int cc2 = cc ^ ((row >> 1) & 3);
      gload_lds16(Abase + (size_t)row * DD + kt * 64 + cc2 * 16,
                  lds + p * 24576 + c * 16);
    }
    // B: 256 rows x 4 chunks = 1024 chunk-loads (4/thread)
    #pragma unroll
    for (int j = 0; j < 4; ++j){
      int c = j * 256 + tid;
      int row = c >> 2, cc = c & 3;
      int cc2 = cc ^ ((row >> 1) & 3);
      gload_lds16(Bbase + (size_t)row * DD + kt * 64 + cc2 * 16,
                  lds + p * 24576 + 8192 + c * 16);
    }
  };
  auto LDA = [&](int p, int mi)->i32x4 {
    int row = wr * 64 + mi * 16 + r;
    return *(const i32x4*)(lds + p * 24576 + row * 64 + ((kg ^ ((row >> 1) & 3)) * 16));
  };
  auto LDB = [&](int p, int ni)->i32x4 {
    int row = wc * 128 + ni * 16 + r;
    return *(const i32x4*)(lds + p * 24576 + 8192 + row * 64 + ((kg ^ ((row >> 1) & 3)) * 16));
  };

  i32x4 acc[4][8];
  #pragma unroll
  for (int mi = 0; mi < 4; ++mi)
    #pragma unroll
    for (int ni = 0; ni < 8; ++ni) acc[mi][ni] = (i32x4){0, 0, 0, 0};

  STAGE(0, 0); STAGE(1, 1);    // 12 loads/thread in flight
  #pragma unroll
  for (int t = 0; t < 12; ++t){
    if (t < 11) asm volatile("s_waitcnt vmcnt(6)" ::: "memory");   // stage(t) landed
    else        asm volatile("s_waitcnt vmcnt(0)" ::: "memory");
    __builtin_amdgcn_s_barrier();
    __builtin_amdgcn_sched_barrier(0);
    const int p = t % 3;
    if (t < 10) STAGE((t + 2) % 3, t + 2);   // buf[(t+2)%3]: readers done at t-1
    i32x4 af[4], bf[8];
    #pragma unroll
    for (int mi = 0; mi < 4; ++mi) af[mi] = LDA(p, mi);
    #pragma unroll
    for (int ni = 0; ni < 8; ++ni) bf[ni] = LDB(p, ni);
    __builtin_amdgcn_s_setprio(1);
    #pragma unroll
    for (int mi = 0; mi < 4; ++mi)
      #pragma unroll
      for (int ni = 0; ni < 8; ++ni) MFMAI8(acc[mi][ni], af[mi], bf[ni]);
    __builtin_amdgcn_s_setprio(0);
  }

  // epilogue: dequant + per-row sum of exp(logit-20). row = by*128 + wr*64 + mi*16 + kg*4 + rr.
  const float SC = TSCALE / 16129.0f;   // 20/127^2
  const int rowbase = by * 128 + wr * 64 + kg * 4;
  #pragma unroll
  for (int mi = 0; mi < 4; ++mi){
    #pragma unroll
    for (int rr = 0; rr < 4; ++rr){
      float s = 0.f;
      #pragma unroll
      for (int ni = 0; ni < 8; ++ni) s += expf(fmaf((float)acc[mi][ni][rr], SC, -TSCALE));
      s += __shfl_xor(s, 1, 64); s += __shfl_xor(s, 2, 64);
      s += __shfl_xor(s, 4, 64); s += __shfl_xor(s, 8, 64);
      if (r == 0) atomicAdd(&sumexp[rowbase + mi * 16 + rr], s);
    }
  }
}

__global__ __launch_bounds__(256) void finalize_kernel(
    const float* __restrict__ sumexp, const float* __restrict__ diagmax,
    const float* __restrict__ rowsum, const float* __restrict__ colsum,
    const float* __restrict__ Ldiag, const float* __restrict__ lossv_arr,
    float* __restrict__ out, int NB)
{
  int tid = threadIdx.x;
  float p = 0.f;
  for (int r = tid; r < 3 * NB; r += 256) p += logf(sumexp[r]) + TSCALE - diagmax[r];
  p *= (0.3f / (3.0f * NB));
  float q = 0.f, lv = 0.f;
  for (int i2 = tid; i2 < NB; i2 += 256){
    q += (logf(rowsum[i2]) + TSCALE - Ldiag[i2]) + (logf(colsum[i2]) + TSCALE - Ldiag[i2]);
    lv += lossv_arr[i2];
  }
  p += q * (0.25f / NB) + lv * (0.2f / NB);
  __shared__ float red[256];
  red[tid] = p; __syncthreads();
  for (int s = 128; s > 0; s >>= 1){ if (tid < s) red[tid] += red[tid + s]; __syncthreads(); }
  if (tid == 0) out[0] = red[0];
}

extern "C" void kernel_launch(void* const* d_in, const int* in_sizes, int n_in,
                              void* d_out, int out_size, void* d_ws, size_t ws_size,
                              hipStream_t stream) {
  const float* obj = (const float*)d_in[0];
  const float* txt = (const float*)d_in[1];
  const float* mdl = (const float*)d_in[2];
  const int*   lab = (const int*)d_in[3];

  const int NB = in_sizes[1] / (4 * DD);   // 1280
  const int C  = in_sizes[2] / NB;          // 504

  float* ws = (float*)d_ws;
  size_t o = 0;
  int8_t* obji8 = (int8_t*)(ws + o); o += (size_t)NB * 8 * DD / 4;   // bytes/4
  int8_t* argi8 = (int8_t*)(ws + o); o += (size_t)NB * 3 * DD / 4;
  __hip_bfloat16* tenb = (__hip_bfloat16*)(ws + o); o += (size_t)NB * DD / 2;
  __hip_bfloat16* venb = (__hip_bfloat16*)(ws + o); o += (size_t)NB * DD / 2;
  float* diagmax = ws + o; o += (size_t)3 * NB;
  float* Ldiag = ws + o; o += (size_t)NB;
  float* lossv_arr = ws + o; o += (size_t)NB;
  float* zr = ws + o;
  float* sumexp = zr;                      // 3*NB
  float* rowsum = zr + 3 * NB;             // NB
  float* colsum = rowsum + NB;             // NB

  diag_teve<<<NB, 512, 0, stream>>>(obj, txt, mdl, lab, diagmax, obji8, argi8,
                                    tenb, venb, lossv_arr, zr, C);
  const int necx = NB / 128;               // 10
  const int nec = necx * necx;             // 100 ec blocks
  const int nwpg = (NB * 3 / 128) * (NB * 8 / 256);   // 30 x 40 = 1200 wpg blocks
  gemms_fused<<<nec + nwpg, 256, 0, stream>>>(argi8, obji8, sumexp, tenb, venb,
                                              rowsum, colsum, Ldiag, nec, necx);
  finalize_kernel<<<1, 256, 0, stream>>>(sumexp, diagmax, rowsum, colsum, Ldiag, lossv_arr,
                                         (float*)d_out, NB);
}

// Round 18
// 87.721 us; speedup vs baseline: 1.5484x; 1.0093x over previous
//
#include <hip/hip_runtime.h>
#include <hip/hip_bf16.h>
#include <cstdint>
#include <cstddef>

#define DD 768
#define TSCALE 20.0f

typedef short bf16x8 __attribute__((ext_vector_type(8)));
typedef float f32x4 __attribute__((ext_vector_type(4)));
typedef int   i32x4 __attribute__((ext_vector_type(4)));

__device__ inline float wsum(float v){
  #pragma unroll
  for (int m = 1; m < 64; m <<= 1) v += __shfl_xor(v, m, 64);
  return v;
}
__device__ inline float wmax(float v){
  #pragma unroll
  for (int m = 1; m < 64; m <<= 1) v = fmaxf(v, __shfl_xor(v, m, 64));
  return v;
}

__device__ inline void gload_lds16(const void* g, void* l){
  __builtin_amdgcn_global_load_lds(
      (const __attribute__((address_space(1))) uint32_t*)g,
      (__attribute__((address_space(3))) uint32_t*)l, 16, 0, 0);
}

__device__ inline void store_bf16x4(__hip_bfloat16* p, float4 x){
  __hip_bfloat16 t[4] = {__float2bfloat16(x.x), __float2bfloat16(x.y),
                         __float2bfloat16(x.z), __float2bfloat16(x.w)};
  *(ushort4*)p = *(const ushort4*)t;
}

// quantize 4 normalized floats (|x|<=1) to int8 at scale 127, packed store
__device__ inline void store_i8x4(int8_t* p, float4 x){
  int q0 = __float2int_rn(x.x * 127.f), q1 = __float2int_rn(x.y * 127.f);
  int q2 = __float2int_rn(x.z * 127.f), q3 = __float2int_rn(x.w * 127.f);
  uint32_t w = (uint32_t)(uint8_t)(int8_t)q0 | ((uint32_t)(uint8_t)(int8_t)q1 << 8) |
               ((uint32_t)(uint8_t)(int8_t)q2 << 16) | ((uint32_t)(uint8_t)(int8_t)q3 << 24);
  *(uint32_t*)p = w;
}

// ====== fused normalize + diag argmax/mask + te/ve + i8 emit + lossv, 8 waves ======
// r18: ALL global loads issued at kernel entry (obj row, txt row, mdl scalars) so
// HBM latencies overlap; phase 3 uses the in-register normalized obj row instead of
// re-reading LDS. Arithmetic orders identical to r15/r17.
__global__ __launch_bounds__(512, 2) void diag_teve(
    const float* __restrict__ obj, const float* __restrict__ txt,
    const float* __restrict__ mdl, const int* __restrict__ lab,
    float* __restrict__ diagmax,
    int8_t* __restrict__ obji8, int8_t* __restrict__ argi8,
    __hip_bfloat16* __restrict__ tenb, __hip_bfloat16* __restrict__ venb,
    float* __restrict__ lossv_arr, float* __restrict__ zr, int C)
{
  __shared__ float so[8][DD];
  __shared__ float sa[3][DD];
  __shared__ float st1[DD];
  __shared__ float sdot[3][8];
  __shared__ float smask[3];
  __shared__ int   sbi[3];
  __shared__ float pmax[4], psum[4];

  const int i = blockIdx.x, tid = threadIdx.x;
  const int lane = tid & 63, w = tid >> 6;

  if (tid < 5) zr[i * 5 + tid] = 0.f;

  // ---- issue ALL global loads upfront (latencies overlap) ----
  float4 v[3];                                   // obj row w
  {
    const float* src = obj + ((size_t)i * 8 + w) * DD;
    #pragma unroll
    for (int q = 0; q < 3; ++q) v[q] = ((const float4*)src)[lane + q * 64];
  }
  float4 a[3];                                   // waves 0-3: txt row
  float x1 = -3.0e38f, x2 = -3.0e38f;            // waves 4-7: mdl scalars
  bool v1 = false, v2 = false;
  if (w < 4){
    int s4 = (w == 0) ? 0 : ((w < 3) ? (w + 1) : 1);
    const float* ap = txt + ((size_t)i * 4 + s4) * DD;
    #pragma unroll
    for (int q = 0; q < 3; ++q) a[q] = ((const float4*)ap)[lane + q * 64];
  } else {
    const int W = w - 4;
    const float* x = mdl + (size_t)i * C;
    int c1 = lane + W * 64, c2 = c1 + 256;
    v1 = c1 < C; v2 = c2 < C;
    if (v1) x1 = x[c1];
    if (v2) x2 = x[c2];
  }

  // ---- phase 1: normalize obj row w (same wsum order) ----
  {
    float ss = 0.f;
    #pragma unroll
    for (int q = 0; q < 3; ++q)
      ss += v[q].x * v[q].x + v[q].y * v[q].y + v[q].z * v[q].z + v[q].w * v[q].w;
    ss = wsum(ss);
    float inv = 1.0f / fmaxf(sqrtf(ss), 1e-12f);
    #pragma unroll
    for (int q = 0; q < 3; ++q){
      float4 x = {v[q].x * inv, v[q].y * inv, v[q].z * inv, v[q].w * inv};
      v[q] = x;                                   // keep normalized row in regs
      ((float4*)&so[w][0])[lane + q * 64] = x;
      store_i8x4(obji8 + ((size_t)i * 8 + w) * DD + 4 * (lane + q * 64), x);
    }
  }

  // ---- phase 2: waves 0-3 normalize txt row; waves 4-7 lossv partials ----
  if (w < 4){
    float ss = 0.f;
    #pragma unroll
    for (int q = 0; q < 3; ++q)
      ss += a[q].x * a[q].x + a[q].y * a[q].y + a[q].z * a[q].z + a[q].w * a[q].w;
    ss = wsum(ss);
    float inv = 1.0f / fmaxf(sqrtf(ss), 1e-12f);
    #pragma unroll
    for (int q = 0; q < 3; ++q){
      a[q].x *= inv; a[q].y *= inv; a[q].z *= inv; a[q].w *= inv;
    }
    if (w < 3){
      #pragma unroll
      for (int q = 0; q < 3; ++q){
        ((float4*)&sa[w][0])[lane + q * 64] = a[q];
        store_i8x4(argi8 + (size_t)(i * 3 + w) * DD + 4 * (lane + q * 64), a[q]);
      }
    } else {
      #pragma unroll
      for (int q = 0; q < 3; ++q) ((float4*)st1)[lane + q * 64] = a[q];
    }
  } else {
    const int W = w - 4;
    float mx = -3.0e38f;
    if (v1) mx = fmaxf(mx, x1);
    if (v2) mx = fmaxf(mx, x2);
    mx = wmax(mx);
    float s = 0.f;
    if (v1) s += expf(x1 - mx);
    if (v2) s += expf(x2 - mx);
    s = wsum(s);
    if (lane == 0){ pmax[W] = mx; psum[W] = s; }
  }
  __syncthreads();

  // ---- phase 3 (parallel): wave w dots sa[j] with its in-register obj row ----
  {
    #pragma unroll
    for (int j = 0; j < 3; ++j){
      float s = 0.f;
      #pragma unroll
      for (int q = 0; q < 3; ++q){
        float4 aq = ((const float4*)&sa[j][0])[lane + q * 64];
        s += aq.x * v[q].x + aq.y * v[q].y + aq.z * v[q].z + aq.w * v[q].w;
      }
      s = wsum(s);
      if (lane == 0) sdot[j][w] = s;
    }
    if (w == 3 && lane == 0){
      float M = fmaxf(fmaxf(pmax[0], pmax[1]), fmaxf(pmax[2], pmax[3]));
      float S = psum[0] * expf(pmax[0] - M) + psum[1] * expf(pmax[1] - M)
              + psum[2] * expf(pmax[2] - M) + psum[3] * expf(pmax[3] - M);
      lossv_arr[i] = logf(S) + M - mdl[(size_t)i * C + lab[i]];
    }
  }
  __syncthreads();

  // ---- phase 4a: wave-0 lanes 0-2: 8-way argmax, strict > (first-index ties) ----
  if (w == 0 && lane < 3){
    float best = -3.0e38f; int bi = 0;
    #pragma unroll
    for (int k = 0; k < 8; ++k){
      float s = sdot[lane][k];
      if (s > best){ best = s; bi = k; }
    }
    float dm = best * TSCALE;
    diagmax[i * 3 + lane] = dm;
    smask[lane] = (dm > 1.0f) ? 1.0f : 0.0f;
    sbi[lane] = bi;
  }
  __syncthreads();

  // ---- phase 4b: wave 0 -> te, wave 1 -> ve (same accumulation order) ----
  if (w == 0){
    float m0 = smask[0], m1 = smask[1], m2 = smask[2];
    float4 te[3]; float ss = 0.f;
    #pragma unroll
    for (int q = 0; q < 3; ++q){
      float4 t1v = ((const float4*)st1)[lane + q * 64];
      float4 a0 = ((const float4*)&sa[0][0])[lane + q * 64];
      float4 a1 = ((const float4*)&sa[1][0])[lane + q * 64];
      float4 a2 = ((const float4*)&sa[2][0])[lane + q * 64];
      float4 t;
      t.x = ((t1v.x + m0 * a0.x) + m1 * a1.x) + m2 * a2.x;
      t.y = ((t1v.y + m0 * a0.y) + m1 * a1.y) + m2 * a2.y;
      t.z = ((t1v.z + m0 * a0.z) + m1 * a1.z) + m2 * a2.z;
      t.w = ((t1v.w + m0 * a0.w) + m1 * a1.w) + m2 * a2.w;
      te[q] = t;
      ss += t.x * t.x + t.y * t.y + t.z * t.z + t.w * t.w;
    }
    ss = wsum(ss);
    float inv = 1.0f / fmaxf(sqrtf(ss), 1e-12f);
    #pragma unroll
    for (int q = 0; q < 3; ++q){
      float4 x = {te[q].x * inv, te[q].y * inv, te[q].z * inv, te[q].w * inv};
      store_bf16x4(tenb + (size_t)i * DD + lane * 4 + q * 256, x);
    }
  } else if (w == 1){
    float m0 = smask[0], m1 = smask[1], m2 = smask[2];
    int b0 = sbi[0], b1 = sbi[1], b2 = sbi[2];
    float4 ve[3]; float ss = 0.f;
    #pragma unroll
    for (int q = 0; q < 3; ++q){
      float4 w0 = ((const float4*)&so[b0][0])[lane + q * 64];
      float4 w1 = ((const float4*)&so[b1][0])[lane + q * 64];
      float4 w2 = ((const float4*)&so[b2][0])[lane + q * 64];
      float4 t;
      t.x = ((m0 * w0.x + m1 * w1.x)) + m2 * w2.x;
      t.y = ((m0 * w0.y + m1 * w1.y)) + m2 * w2.y;
      t.z = ((m0 * w0.z + m1 * w1.z)) + m2 * w2.z;
      t.w = ((m0 * w0.w + m1 * w1.w)) + m2 * w2.w;
      ve[q] = t;
      ss += t.x * t.x + t.y * t.y + t.z * t.z + t.w * t.w;
    }
    ss = wsum(ss);
    float inv = 1.0f / fmaxf(sqrtf(ss), 1e-12f);
    #pragma unroll
    for (int q = 0; q < 3; ++q){
      float4 x = {ve[q].x * inv, ve[q].y * inv, ve[q].z * inv, ve[q].w * inv};
      store_bf16x4(venb + (size_t)i * DD + lane * 4 + q * 256, x);
    }
  }
}

// ====== unified GEMM kernel: blocks [0,nec) = ec (bf16), rest = wpg (i8) ======
// (frozen r17 best: 128x256 block, 64x128/wave, BK=64B, 3-buffer 72KB LDS,
// counted vmcnt(6), 2 blocks/CU.)
#define MFMAI8(d, av, bv) d = __builtin_amdgcn_mfma_i32_16x16x64_i8(av, bv, d, 0, 0, 0)

__global__ __launch_bounds__(256, 2) void gemms_fused(
    const int8_t* __restrict__ A, const int8_t* __restrict__ B,
    float* __restrict__ sumexp,
    const __hip_bfloat16* __restrict__ ten, const __hip_bfloat16* __restrict__ ven,
    float* __restrict__ rowsum, float* __restrict__ colsum, float* __restrict__ Ldiag,
    int nec, int necx)
{
  __shared__ char lds[73728];
  const int tid = threadIdx.x;
  const int lane = tid & 63, wid = tid >> 6;

  if ((int)blockIdx.x < nec){
    // ---------------- ec path (unchanged) ----------------
    const int bx = blockIdx.x % necx, by = blockIdx.x / necx;
    __hip_bfloat16* As = (__hip_bfloat16*)lds;
    __hip_bfloat16* Bs = (__hip_bfloat16*)(lds + 8192);
    char* AsB = lds; char* BsB = lds + 8192;
    const int wr = wid >> 1, wc = wid & 1;
    f32x4 acc[4][4];
    #pragma unroll
    for (int i2 = 0; i2 < 4; ++i2)
      #pragma unroll
      for (int j = 0; j < 4; ++j) acc[i2][j] = (f32x4){0.f, 0.f, 0.f, 0.f};
    const char* Ab = (const char*)(ten + (size_t)(by * 128) * DD);
    const char* Bb = (const char*)(ven + (size_t)(bx * 128) * DD);
    const int srow = tid >> 2, scol = (tid & 3) * 16;
    const int r = lane & 15, kg = (lane >> 4) * 8;

    for (int kb = 0; kb < DD * 2; kb += 64){
      gload_lds16(Ab + (size_t)srow * (DD*2) + kb + scol, AsB + tid * 16);
      gload_lds16(Ab + (size_t)(srow + 64) * (DD*2) + kb + scol, AsB + 4096 + tid * 16);
      gload_lds16(Bb + (size_t)srow * (DD*2) + kb + scol, BsB + tid * 16);
      gload_lds16(Bb + (size_t)(srow + 64) * (DD*2) + kb + scol, BsB + 4096 + tid * 16);
      __syncthreads();
      bf16x8 af[4], bfr[4];
      #pragma unroll
      for (int mi = 0; mi < 4; ++mi)
        af[mi] = *(const bf16x8*)&As[(wr * 64 + mi * 16 + r) * 32 + kg];
      #pragma unroll
      for (int ni = 0; ni < 4; ++ni)
        bfr[ni] = *(const bf16x8*)&Bs[(wc * 64 + ni * 16 + r) * 32 + kg];
      #pragma unroll
      for (int mi = 0; mi < 4; ++mi)
        #pragma unroll
        for (int ni = 0; ni < 4; ++ni)
          acc[mi][ni] = __builtin_amdgcn_mfma_f32_16x16x32_bf16(af[mi], bfr[ni], acc[mi][ni], 0, 0, 0);
      __syncthreads();
    }
    int rowbase = by * 128 + wr * 64 + ((lane >> 4) << 2);
    float colacc[4] = {0.f, 0.f, 0.f, 0.f};
    #pragma unroll
    for (int mi = 0; mi < 4; ++mi){
      #pragma unroll
      for (int rr = 0; rr < 4; ++rr){
        float s = 0.f;
        #pragma unroll
        for (int ni = 0; ni < 4; ++ni){
          float e = expf(fmaf(acc[mi][ni][rr], TSCALE, -TSCALE));
          s += e; colacc[ni] += e;
        }
        s += __shfl_xor(s, 1, 64); s += __shfl_xor(s, 2, 64);
        s += __shfl_xor(s, 4, 64); s += __shfl_xor(s, 8, 64);
        if ((lane & 15) == 0) atomicAdd(&rowsum[rowbase + mi * 16 + rr], s);
      }
    }
    #pragma unroll
    for (int ni = 0; ni < 4; ++ni){
      float c = colacc[ni];
      c += __shfl_xor(c, 16, 64); c += __shfl_xor(c, 32, 64);
      if (lane < 16) atomicAdd(&colsum[bx * 128 + wc * 64 + ni * 16 + lane], c);
    }
    if (bx == by){
      #pragma unroll
      for (int mi = 0; mi < 4; ++mi)
        #pragma unroll
        for (int ni = 0; ni < 4; ++ni)
          #pragma unroll
          for (int rr = 0; rr < 4; ++rr){
            int grow = wr * 64 + mi * 16 + ((lane >> 4) << 2) + rr;
            int gcol = wc * 64 + ni * 16 + (lane & 15);
            if (grow == gcol) Ldiag[by * 128 + grow] = acc[mi][ni][rr] * TSCALE;
          }
    }
    return;
  }

  // -------- wpg path: i8 128x256 block, 64x128/wave, 3-buffer counted pipeline --------
  const int wr = wid >> 1, wc = wid & 1;      // 2x2 waves: 64 M x 128 N each
  const int r = lane & 15, kg = lane >> 4;

  int g = blockIdx.x - nec;                    // [0, 1200)
  int bx = (g & 7) * 5 + (g >> 3) % 5;         // 40 N-tiles (256 cols), 5 per XCD
  int by = (g >> 3) / 5;                       // 30 M-tiles (128 rows)

  const int8_t* Abase = A + (size_t)by * 128 * DD;
  const int8_t* Bbase = B + (size_t)bx * 256 * DD;

  auto STAGE = [&](int p, int kt){
    #pragma unroll
    for (int j = 0; j < 2; ++j){
      int c = j * 256 + tid;
      int row = c >> 2, cc = c & 3;
      int cc2 = cc ^ ((row >> 1) & 3);
      gload_lds16(Abase + (size_t)row * DD + kt * 64 + cc2 * 16,
                  lds + p * 24576 + c * 16);
    }
    #pragma unroll
    for (int j = 0; j < 4; ++j){
      int c = j * 256 + tid;
      int row = c >> 2, cc = c & 3;
      int cc2 = cc ^ ((row >> 1) & 3);
      gload_lds16(Bbase + (size_t)row * DD + kt * 64 + cc2 * 16,
                  lds + p * 24576 + 8192 + c * 16);
    }
  };
  auto LDA = [&](int p, int mi)->i32x4 {
    int row = wr * 64 + mi * 16 + r;
    return *(const i32x4*)(lds + p * 24576 + row * 64 + ((kg ^ ((row >> 1) & 3)) * 16));
  };
  auto LDB = [&](int p, int ni)->i32x4 {
    int row = wc * 128 + ni * 16 + r;
    return *(const i32x4*)(lds + p * 24576 + 8192 + row * 64 + ((kg ^ ((row >> 1) & 3)) * 16));
  };

  i32x4 acc[4][8];
  #pragma unroll
  for (int mi = 0; mi < 4; ++mi)
    #pragma unroll
    for (int ni = 0; ni < 8; ++ni) acc[mi][ni] = (i32x4){0, 0, 0, 0};

  STAGE(0, 0); STAGE(1, 1);    // 12 loads/thread in flight
  #pragma unroll
  for (int t = 0; t < 12; ++t){
    if (t < 11) asm volatile("s_waitcnt vmcnt(6)" ::: "memory");   // stage(t) landed
    else        asm volatile("s_waitcnt vmcnt(0)" ::: "memory");
    __builtin_amdgcn_s_barrier();
    __builtin_amdgcn_sched_barrier(0);
    const int p = t % 3;
    if (t < 10) STAGE((t + 2) % 3, t + 2);   // buf[(t+2)%3]: readers done at t-1
    i32x4 af[4], bf[8];
    #pragma unroll
    for (int mi = 0; mi < 4; ++mi) af[mi] = LDA(p, mi);
    #pragma unroll
    for (int ni = 0; ni < 8; ++ni) bf[ni] = LDB(p, ni);
    __builtin_amdgcn_s_setprio(1);
    #pragma unroll
    for (int mi = 0; mi < 4; ++mi)
      #pragma unroll
      for (int ni = 0; ni < 8; ++ni) MFMAI8(acc[mi][ni], af[mi], bf[ni]);
    __builtin_amdgcn_s_setprio(0);
  }

  // epilogue: dequant + per-row sum of exp(logit-20)
  const float SC = TSCALE / 16129.0f;   // 20/127^2
  const int rowbase = by * 128 + wr * 64 + kg * 4;
  #pragma unroll
  for (int mi = 0; mi < 4; ++mi){
    #pragma unroll
    for (int rr = 0; rr < 4; ++rr){
      float s = 0.f;
      #pragma unroll
      for (int ni = 0; ni < 8; ++ni) s += expf(fmaf((float)acc[mi][ni][rr], SC, -TSCALE));
      s += __shfl_xor(s, 1, 64); s += __shfl_xor(s, 2, 64);
      s += __shfl_xor(s, 4, 64); s += __shfl_xor(s, 8, 64);
      if (r == 0) atomicAdd(&sumexp[rowbase + mi * 16 + rr], s);
    }
  }
}

__global__ __launch_bounds__(256) void finalize_kernel(
    const float* __restrict__ sumexp, const float* __restrict__ diagmax,
    const float* __restrict__ rowsum, const float* __restrict__ colsum,
    const float* __restrict__ Ldiag, const float* __restrict__ lossv_arr,
    float* __restrict__ out, int NB)
{
  int tid = threadIdx.x;
  float p = 0.f;
  for (int r = tid; r < 3 * NB; r += 256) p += logf(sumexp[r]) + TSCALE - diagmax[r];
  p *= (0.3f / (3.0f * NB));
  float q = 0.f, lv = 0.f;
  for (int i2 = tid; i2 < NB; i2 += 256){
    q += (logf(rowsum[i2]) + TSCALE - Ldiag[i2]) + (logf(colsum[i2]) + TSCALE - Ldiag[i2]);
    lv += lossv_arr[i2];
  }
  p += q * (0.25f / NB) + lv * (0.2f / NB);
  __shared__ float red[256];
  red[tid] = p; __syncthreads();
  for (int s = 128; s > 0; s >>= 1){ if (tid < s) red[tid] += red[tid + s]; __syncthreads(); }
  if (tid == 0) out[0] = red[0];
}

extern "C" void kernel_launch(void* const* d_in, const int* in_sizes, int n_in,
                              void* d_out, int out_size, void* d_ws, size_t ws_size,
                              hipStream_t stream) {
  const float* obj = (const float*)d_in[0];
  const float* txt = (const float*)d_in[1];
  const float* mdl = (const float*)d_in[2];
  const int*   lab = (const int*)d_in[3];

  const int NB = in_sizes[1] / (4 * DD);   // 1280
  const int C  = in_sizes[2] / NB;          // 504

  float* ws = (float*)d_ws;
  size_t o = 0;
  int8_t* obji8 = (int8_t*)(ws + o); o += (size_t)NB * 8 * DD / 4;   // bytes/4
  int8_t* argi8 = (int8_t*)(ws + o); o += (size_t)NB * 3 * DD / 4;
  __hip_bfloat16* tenb = (__hip_bfloat16*)(ws + o); o += (size_t)NB * DD / 2;
  __hip_bfloat16* venb = (__hip_bfloat16*)(ws + o); o += (size_t)NB * DD / 2;
  float* diagmax = ws + o; o += (size_t)3 * NB;
  float* Ldiag = ws + o; o += (size_t)NB;
  float* lossv_arr = ws + o; o += (size_t)NB;
  float* zr = ws + o;
  float* sumexp = zr;                      // 3*NB
  float* rowsum = zr + 3 * NB;             // NB
  float* colsum = rowsum + NB;             // NB

  diag_teve<<<NB, 512, 0, stream>>>(obj, txt, mdl, lab, diagmax, obji8, argi8,
                                    tenb, venb, lossv_arr, zr, C);
  const int necx = NB / 128;               // 10
  const int nec = necx * necx;             // 100 ec blocks
  const int nwpg = (NB * 3 / 128) * (NB * 8 / 256);   // 30 x 40 = 1200 wpg blocks
  gemms_fused<<<nec + nwpg, 256, 0, stream>>>(argi8, obji8, sumexp, tenb, venb,
                                              rowsum, colsum, Ldiag, nec, necx);
  finalize_kernel<<<1, 256, 0, stream>>>(sumexp, diagmax, rowsum, colsum, Ldiag, lossv_arr,
                                         (float*)d_out, NB);
}